// Round 6
// baseline (1079.574 us; speedup 1.0000x reference)
//
#include <hip/hip_runtime.h>
#include <math.h>

#define BB 4
#define NN 1024
#define KK 512
#define HH 8
#define DHh 64
#define HIDd 2048
#define BN (BB*NN)

typedef unsigned short u16;
typedef __attribute__((ext_vector_type(8))) short bf16x8;
typedef __attribute__((ext_vector_type(4))) float f32x4;

// ---------------------------------------------------------------- helpers
__device__ __forceinline__ float gelu_tanh(float x){
    float x3 = x*x*x;
    float t = tanhf(0.7978845608028654f*(x + 0.044715f*x3));
    return 0.5f*x*(1.0f+t);
}
__device__ __forceinline__ u16 f2bf(float x){
    unsigned int u = __float_as_uint(x);
    unsigned int r = (u + 0x7fffu + ((u>>16)&1u)) >> 16;
    return (u16)r;
}
__device__ __forceinline__ float bf2f(u16 b){
    return __uint_as_float(((unsigned int)b)<<16);
}
__device__ __forceinline__ void gload16(const void* g, void* l){
    __builtin_amdgcn_global_load_lds((__attribute__((address_space(1))) void*)g,
                                     (__attribute__((address_space(3))) void*)l, 16, 0, 0);
}
__device__ __forceinline__ void wsplit(u16* hi, u16* lo, size_t o, float v){
    u16 h = f2bf(v);
    hi[o] = h;
    lo[o] = f2bf(v - bf2f(h));
}

// ---------------------------------------------------------------- split conversions
__global__ __launch_bounds__(256) void split_k(const float* __restrict__ src,
                                               u16* __restrict__ hi, u16* __restrict__ lo, long n){
    long i = (long)blockIdx.x*256 + threadIdx.x;
    if (i >= n) return;
    wsplit(hi, lo, i, src[i]);
}

// src [Kc][Nc] (row-major, +batch stride sS) -> dst [Nc][Kc] hi/lo bf16 (+batch sD). square opt.
__global__ __launch_bounds__(256) void split_t_k(
    const float* __restrict__ src, u16* __restrict__ hi, u16* __restrict__ lo,
    int Kc, int Nc, long sS, long sD, int square)
{
    __shared__ float t[32][33];
    const int n0 = blockIdx.x*32, k0 = blockIdx.y*32, bz = blockIdx.z;
    const float* S = src + (long)bz*sS;
    const int tx = threadIdx.x & 31, ty = threadIdx.x >> 5;
    for (int r = ty; r < 32; r += 8){
        float v = S[(long)(k0+r)*Nc + n0+tx];
        if (square) v *= v;
        t[r][tx] = v;
    }
    __syncthreads();
    for (int r = ty; r < 32; r += 8){
        float v = t[tx][r];
        long o = (long)bz*sD + (long)(n0+r)*Kc + k0 + tx;
        wsplit(hi, lo, o, v);
    }
}

// gen (3,K,K) -> Gflat[k][g*512+l] split bf16  (B layout [512][1536])
__global__ __launch_bounds__(256) void gflat_k(const float* __restrict__ gen,
                                               u16* __restrict__ hi, u16* __restrict__ lo){
    int idx = blockIdx.x*256 + threadIdx.x;
    if (idx >= 3*KK*KK) return;
    int g = idx / (KK*KK);
    int rem = idx % (KK*KK);
    int k = rem / KK, l = rem % KK;
    wsplit(hi, lo, (size_t)k*(3*KK) + g*KK + l, gen[idx]);
}

// x3[i, g*512+l] = sign*phi[i,g]*x[i,l]  split bf16
__global__ __launch_bounds__(256) void expand3_k(
    const float* __restrict__ x, const float* __restrict__ phi,
    u16* __restrict__ xh, u16* __restrict__ xl, float sign)
{
    int idx = blockIdx.x*256 + threadIdx.x;
    if (idx >= BN*KK/4) return;
    int r = idx >> 7;
    int c4 = (idx & 127) << 2;
    const float* ph = phi + r*3;
    float4 v = *(const float4*)(x + (long)r*KK + c4);
    #pragma unroll
    for (int g=0; g<3; ++g){
        float p = sign*ph[g];
        size_t b = (size_t)r*(3*KK) + g*KK + c4;
        wsplit(xh, xl, b+0, p*v.x); wsplit(xh, xl, b+1, p*v.y);
        wsplit(xh, xl, b+2, p*v.z); wsplit(xh, xl, b+3, p*v.w);
    }
}

// ---------------------------------------------------------------- MFMA GEMM 128x128 (split bf16)
// C = A*B^T, AhBh+AhBl+AlBh.  A: [M][lda] hi/lo.  B: [Nc][Kc] hi/lo.
// cskip: 1 = skip blocks n0>m0+127 (causal S).
__global__ __launch_bounds__(256) void gemm_mfma_k(
    const u16* __restrict__ Ah, const u16* __restrict__ Al,
    const u16* __restrict__ Bh, const u16* __restrict__ Bl,
    float* __restrict__ C, u16* __restrict__ Chi, u16* __restrict__ Clo,
    int M, int Kc, int Nc, int lda,
    long sA, long sB, long sC, const float* __restrict__ bias, int act, int cskip)
{
    __shared__ u16 sAh[128*32], sAl[128*32], sBh[128*32], sBl[128*32];  // 32 KB
    const int m0 = blockIdx.y*128, n0 = blockIdx.x*128;
    if (cskip == 1 && n0 > m0 + 127) return;
    const int bz = blockIdx.z;
    const u16* gAh = Ah + (long)bz*sA;
    const u16* gAl = Al + (long)bz*sA;
    const u16* gBh = Bh + (long)bz*sB;
    const u16* gBl = Bl + (long)bz*sB;
    const int tid = threadIdx.x;
    const int wave = tid >> 6, lane = tid & 63;
    const int quad = lane >> 4, r16 = lane & 15;
    const int wm = (wave>>1)*64, wn = (wave&1)*64;

    f32x4 acc[4][4];
    #pragma unroll
    for (int i=0;i<4;i++)
        #pragma unroll
        for (int j=0;j<4;j++) acc[i][j] = (f32x4){0.f,0.f,0.f,0.f};

    for (int k0 = 0; k0 < Kc; k0 += 32){
        __syncthreads();
        #pragma unroll
        for (int half=0; half<2; ++half){
            int c = half*256 + tid;
            int row = c >> 2, kg = (c & 3)*8;
            long ga = (long)(m0+row)*lda + k0 + kg;
            long gb = (long)(n0+row)*Kc + k0 + kg;
            gload16(gAh+ga, &sAh[c*8]);
            gload16(gAl+ga, &sAl[c*8]);
            gload16(gBh+gb, &sBh[c*8]);
            gload16(gBl+gb, &sBl[c*8]);
        }
        __syncthreads();
        bf16x8 afh[4], afl[4], bfh[4], bfl[4];
        #pragma unroll
        for (int i=0;i<4;i++){
            afh[i] = *(const bf16x8*)&sAh[(wm+i*16+r16)*32 + quad*8];
            afl[i] = *(const bf16x8*)&sAl[(wm+i*16+r16)*32 + quad*8];
            bfh[i] = *(const bf16x8*)&sBh[(wn+i*16+r16)*32 + quad*8];
            bfl[i] = *(const bf16x8*)&sBl[(wn+i*16+r16)*32 + quad*8];
        }
        #pragma unroll
        for (int i=0;i<4;i++)
            #pragma unroll
            for (int j=0;j<4;j++){
                acc[i][j] = __builtin_amdgcn_mfma_f32_16x16x32_bf16(afh[i], bfh[j], acc[i][j], 0,0,0);
                acc[i][j] = __builtin_amdgcn_mfma_f32_16x16x32_bf16(afh[i], bfl[j], acc[i][j], 0,0,0);
                acc[i][j] = __builtin_amdgcn_mfma_f32_16x16x32_bf16(afl[i], bfh[j], acc[i][j], 0,0,0);
            }
    }
    #pragma unroll
    for (int i=0;i<4;i++){
        #pragma unroll
        for (int j=0;j<4;j++){
            int gc = n0 + wn + j*16 + r16;
            if (gc >= Nc) continue;
            float bv = bias ? bias[gc] : 0.f;
            #pragma unroll
            for (int r=0;r<4;r++){
                long gr = m0 + wm + i*16 + quad*4 + r;
                float v = acc[i][j][r] + bv;
                if (act) v = gelu_tanh(v);
                long o = (long)bz*sC + gr*Nc + gc;
                if (C) C[o] = v;
                if (Chi) wsplit(Chi, Clo, o, v);
            }
        }
    }
}

// ---------------------------------------------------------------- MFMA GEMM 64x64 tile (high-occupancy, K-trim)
// For bmh: A = beta_m [M][lda] lower-triangular (K trimmed to m0+64), B [Nc][Kc].
__global__ __launch_bounds__(256) void gemm64_k(
    const u16* __restrict__ Ah, const u16* __restrict__ Al,
    const u16* __restrict__ Bh, const u16* __restrict__ Bl,
    float* __restrict__ C, int M, int Kc, int Nc, int lda,
    long sA, long sB, long sC)
{
    __shared__ u16 sAh[64*32], sAl[64*32], sBh[64*32], sBl[64*32];  // 16 KB
    const int m0 = blockIdx.y*64, n0 = blockIdx.x*64;
    const int bz = blockIdx.z;
    const u16* gAh = Ah + (long)bz*sA;
    const u16* gAl = Al + (long)bz*sA;
    const u16* gBh = Bh + (long)bz*sB;
    const u16* gBl = Bl + (long)bz*sB;
    const int tid = threadIdx.x;
    const int wave = tid >> 6, lane = tid & 63;
    const int quad = lane >> 4, r16 = lane & 15;
    const int wr = wave*16;
    const int kend = min(Kc, m0 + 64);

    f32x4 acc[4];
    #pragma unroll
    for (int j=0;j<4;j++) acc[j] = (f32x4){0.f,0.f,0.f,0.f};

    for (int k0 = 0; k0 < kend; k0 += 32){
        __syncthreads();
        {
            int row = tid >> 2, kg = (tid & 3)*8;
            long ga = (long)(m0+row)*lda + k0 + kg;
            long gb = (long)(n0+row)*Kc + k0 + kg;
            gload16(gAh+ga, &sAh[tid*8]);
            gload16(gAl+ga, &sAl[tid*8]);
            gload16(gBh+gb, &sBh[tid*8]);
            gload16(gBl+gb, &sBl[tid*8]);
        }
        __syncthreads();
        bf16x8 afh = *(const bf16x8*)&sAh[(wr+r16)*32 + quad*8];
        bf16x8 afl = *(const bf16x8*)&sAl[(wr+r16)*32 + quad*8];
        #pragma unroll
        for (int j=0;j<4;j++){
            bf16x8 bh = *(const bf16x8*)&sBh[(j*16+r16)*32 + quad*8];
            bf16x8 bl = *(const bf16x8*)&sBl[(j*16+r16)*32 + quad*8];
            acc[j] = __builtin_amdgcn_mfma_f32_16x16x32_bf16(afh, bh, acc[j], 0,0,0);
            acc[j] = __builtin_amdgcn_mfma_f32_16x16x32_bf16(afh, bl, acc[j], 0,0,0);
            acc[j] = __builtin_amdgcn_mfma_f32_16x16x32_bf16(afl, bh, acc[j], 0,0,0);
        }
    }
    #pragma unroll
    for (int j=0;j<4;j++){
        int gc = n0 + j*16 + r16;
        #pragma unroll
        for (int r=0;r<4;r++){
            long gr = m0 + wr + quad*4 + r;
            C[(long)bz*sC + gr*Nc + gc] = acc[j][r];
        }
    }
}

// ---------------------------------------------------------------- LayerNorm (rows of 512), optional split out
__global__ __launch_bounds__(256) void ln_k(
    const float* __restrict__ x, const float* __restrict__ g,
    const float* __restrict__ be, float* __restrict__ y,
    u16* __restrict__ yh, u16* __restrict__ yl)
{
    __shared__ float sh[8];
    const int r = blockIdx.x, tid = threadIdx.x;
    const float* xr = x + (long)r*KK;
    float2 v = *(const float2*)(xr + tid*2);
    float s = v.x+v.y, s2 = v.x*v.x+v.y*v.y;
    #pragma unroll
    for (int o=32;o>0;o>>=1){ s += __shfl_down(s,o); s2 += __shfl_down(s2,o); }
    if ((tid&63)==0){ sh[tid>>6]=s; sh[4+(tid>>6)]=s2; }
    __syncthreads();
    s  = sh[0]+sh[1]+sh[2]+sh[3];
    s2 = sh[4]+sh[5]+sh[6]+sh[7];
    const float mean = s*(1.f/KK);
    const float var  = s2*(1.f/KK) - mean*mean;
    const float rs = rsqrtf(var + 1e-5f);
    float2 gg = *(const float2*)(g + tid*2);
    float2 bb = *(const float2*)(be + tid*2);
    float ox = (v.x-mean)*rs*gg.x + bb.x;
    float oy = (v.y-mean)*rs*gg.y + bb.y;
    long o = (long)r*KK + tid*2;
    *(float2*)(y + o) = make_float2(ox, oy);
    if (yh){ wsplit(yh, yl, o, ox); wsplit(yh, yl, o+1, oy); }
}

// ---------------------------------------------------------------- elementwise kernels
// out = (res?res:0) + x + a1 + 0.5*a2, optional split
__global__ void tfinal_k(const float* __restrict__ x, const float* __restrict__ a1,
                         const float* __restrict__ a2, const float* __restrict__ res,
                         float* __restrict__ out, u16* __restrict__ oh, u16* __restrict__ ol){
    int i = blockIdx.x*256 + threadIdx.x;
    if (i >= BN*KK/4) return;
    float4 xv = ((const float4*)x)[i];
    float4 v1 = ((const float4*)a1)[i];
    float4 v2 = ((const float4*)a2)[i];
    float4 o;
    o.x = xv.x + v1.x + 0.5f*v2.x;
    o.y = xv.y + v1.y + 0.5f*v2.y;
    o.z = xv.z + v1.z + 0.5f*v2.z;
    o.w = xv.w + v1.w + 0.5f*v2.w;
    if (res){ float4 rv = ((const float4*)res)[i]; o.x+=rv.x; o.y+=rv.y; o.z+=rv.z; o.w+=rv.w; }
    ((float4*)out)[i] = o;
    if (oh){
        long ob = (long)i*4;
        wsplit(oh, ol, ob+0, o.x); wsplit(oh, ol, ob+1, o.y);
        wsplit(oh, ol, ob+2, o.z); wsplit(oh, ol, ob+3, o.w);
    }
}
__global__ void copy_k(const float* __restrict__ s, float* __restrict__ d, int n4){
    int i = blockIdx.x*256 + threadIdx.x;
    if (i < n4) ((float4*)d)[i] = ((const float4*)s)[i];
}
__global__ void final_k(const float* __restrict__ a, const float* __restrict__ b,
                        const float* __restrict__ c, float* __restrict__ out){
    int i = blockIdx.x*256 + threadIdx.x;
    if (i >= BN*KK/4) return;
    float4 av = ((const float4*)a)[i], bv = ((const float4*)b)[i], cv = ((const float4*)c)[i];
    float4 o;
    o.x = av.x + bv.x - cv.x; o.y = av.y + bv.y - cv.y;
    o.z = av.z + bv.z - cv.z; o.w = av.w + bv.w - cv.w;
    ((float4*)out)[i] = o;
}
// h_out = h_in + lr*(drive - grad); also split h_out
__global__ void ffn_update_k(const float* __restrict__ hin, float* __restrict__ hout,
                             const float* __restrict__ drive, const float* __restrict__ bmh,
                             const float* __restrict__ mup, const float* __restrict__ lr,
                             u16* __restrict__ hh, u16* __restrict__ hl){
    int i = blockIdx.x*256 + threadIdx.x;
    if (i >= BN*KK/4) return;
    const float lrv = *lr;
    float4 hv = ((const float4*)hin)[i];
    float4 dv = ((const float4*)drive)[i];
    float4 bv = ((const float4*)bmh)[i];
    float4 pv = ((const float4*)mup)[i];
    float4 o;
    o.x = hv.x + lrv*(dv.x - (1e-3f*(hv.x-pv.x) + 1.0f*(hv.x-bv.x)));
    o.y = hv.y + lrv*(dv.y - (1e-3f*(hv.y-pv.y) + 1.0f*(hv.y-bv.y)));
    o.z = hv.z + lrv*(dv.z - (1e-3f*(hv.z-pv.z) + 1.0f*(hv.z-bv.z)));
    o.w = hv.w + lrv*(dv.w - (1e-3f*(hv.w-pv.w) + 1.0f*(hv.w-bv.w)));
    ((float4*)hout)[i] = o;
    long ob = (long)i*4;
    wsplit(hh, hl, ob+0, o.x); wsplit(hh, hl, ob+1, o.y);
    wsplit(hh, hl, ob+2, o.z); wsplit(hh, hl, ob+3, o.w);
}

// ---------------------------------------------------------------- attention prep (QKV stride 1536, SQSK stride 1024)
__global__ __launch_bounds__(512) void prep2_k(
    const float* __restrict__ QKV, const float* __restrict__ SQSK,
    u16* __restrict__ CFh, u16* __restrict__ CFl,
    u16* __restrict__ KSh, u16* __restrict__ KSl, float* __restrict__ dvec)
{
    const int bn = blockIdx.x;
    const int b = bn / NN, n = bn % NN;
    const int h = threadIdx.x >> 6, d = threadIdx.x & 63;
    float q  = QKV[(size_t)bn*1536 + h*DHh + d];
    float k  = QKV[(size_t)bn*1536 + KK + h*DHh + d];
    float sq = SQSK[(size_t)bn*1024 + h*DHh + d] + 1e-8f;
    float sk = SQSK[(size_t)bn*1024 + KK + h*DHh + d] + 1e-8f;
    float inv = 1.f/sq;
    float nqi = -2.f*q*inv;
    float skk = sk + k*k;
    const size_t base = ((size_t)(h*BB + b)*NN + n)*128;
    wsplit(CFh, CFl, base+d,    inv);
    wsplit(CFh, CFl, base+64+d, nqi);
    wsplit(KSh, KSl, base+d,    skk);
    wsplit(KSh, KSl, base+64+d, k);
    float dv = __logf(sk);
    #pragma unroll
    for (int o=32;o>0;o>>=1) dv += __shfl_down(dv,o);
    if (d==0) dvec[((size_t)h*BB + b)*NN + n] = dv;
}

// ---------------------------------------------------------------- V transpose+split: QKV (stride 1536, off 1024) -> (H*BB, 64, NN)
__global__ __launch_bounds__(256) void vtsplit_k(
    const float* __restrict__ QKV, u16* __restrict__ VTh, u16* __restrict__ VTl)
{
    __shared__ float t[64][65];
    const int n0 = blockIdx.x * 64;
    const int h = blockIdx.y, b = blockIdx.z;
    const int tid = threadIdx.x;
    const int c4 = (tid & 15) * 4;
    const int r0 = tid >> 4;
    for (int rr = r0; rr < 64; rr += 16){
        float4 v = *(const float4*)(QKV + (size_t)(b*NN + n0 + rr)*1536 + 1024 + h*DHh + c4);
        t[c4+0][rr] = v.x; t[c4+1][rr] = v.y; t[c4+2][rr] = v.z; t[c4+3][rr] = v.w;
    }
    __syncthreads();
    for (int dd = r0; dd < 64; dd += 16){
        size_t base = ((size_t)(h*BB + b)*64 + dd)*NN + n0 + c4;
        #pragma unroll
        for (int q=0;q<4;q++) wsplit(VTh, VTl, base+q, t[dd][c4+q]);
    }
}

// ---------------------------------------------------------------- softmax for a head-group of 4
__global__ __launch_bounds__(256) void softmax2_k(
    float* __restrict__ S, const float* __restrict__ dvec,
    float* __restrict__ betam, u16* __restrict__ BMh, u16* __restrict__ BMl, int g)
{
    __shared__ float s_sc[NN];
    __shared__ float s_bm[NN];
    __shared__ float s_red[4];
    const int tid = threadIdx.x;
    const int b = blockIdx.x / NN, i = blockIdx.x % NN;
    const int L = i + 1;
    for (int j=tid;j<NN;j+=256) s_bm[j]=0.f;
    for (int hg=0; hg<4; ++hg){
        const int z = hg*BB + b;
        float* row = S + ((long)z*NN + i)*NN;
        const float* dp = dvec + ((size_t)(g*4+hg)*BB + b)*NN;
        float lm = -3.0e38f;
        for (int j=tid;j<L;j+=256){
            float sc = -0.5f*row[j] + 0.5f*dp[j];
            s_sc[j] = sc;
            lm = fmaxf(lm, sc);
        }
        #pragma unroll
        for (int o=32;o>0;o>>=1) lm = fmaxf(lm, __shfl_xor(lm, o));
        __syncthreads();
        if ((tid&63)==0) s_red[tid>>6] = lm;
        __syncthreads();
        const float mx = fmaxf(fmaxf(s_red[0],s_red[1]), fmaxf(s_red[2],s_red[3]));
        float ps = 0.f;
        for (int j=tid;j<L;j+=256){
            float e = __expf(s_sc[j]-mx);
            s_sc[j] = e;
            ps += e;
        }
        #pragma unroll
        for (int o=32;o>0;o>>=1) ps += __shfl_xor(ps, o);
        __syncthreads();
        if ((tid&63)==0) s_red[tid>>6] = ps;
        __syncthreads();
        const float isum = 1.f/(s_red[0]+s_red[1]+s_red[2]+s_red[3]);
        u16* brow = (u16*)row;
        for (int j=tid;j<NN;j+=256){
            if (j < L){
                float w = s_sc[j]*isum;
                brow[j] = f2bf(w);
                s_bm[j] += 0.125f*w;
            } else {
                brow[j] = 0;
            }
        }
        __syncthreads();
    }
    const long bmrow = ((long)b*NN + i)*NN;
    if (g == 0){
        for (int j=tid;j<NN;j+=256) betam[bmrow+j] = s_bm[j];
    } else {
        for (int j=tid;j<NN;j+=256){
            float v = betam[bmrow+j] + s_bm[j];
            wsplit(BMh, BMl, bmrow+j, v);
        }
    }
}

// ---------------------------------------------------------------- PV: out[i,d] = sum_j beta[i,j] V[j,d]
__global__ __launch_bounds__(256) void pv_k(
    const u16* __restrict__ Sbeta,
    const u16* __restrict__ VTh, const u16* __restrict__ VTl,
    float* __restrict__ x, u16* __restrict__ xh, u16* __restrict__ xl, int g)
{
    __shared__ u16 sA[64*64];
    __shared__ u16 sBh[64*64];
    __shared__ u16 sBl[64*64];
    const int m0 = blockIdx.x*64;
    const int z16 = blockIdx.y;
    const int b = z16 & 3, hg = z16 >> 2;
    const int head = g*4 + hg;
    const int vtz = head*BB + b;
    const int tid = threadIdx.x;
    const int wave = tid>>6, lane = tid&63;
    const int quad = lane>>4, r16 = lane&15;
    f32x4 acc[4];
    #pragma unroll
    for (int j=0;j<4;j++) acc[j]=(f32x4){0.f,0.f,0.f,0.f};
    const int jmax = m0 + 64;
    for (int j0 = 0; j0 < jmax; j0 += 64){
        __syncthreads();
        int c = tid;
        #pragma unroll
        for (int rep=0; rep<2; ++rep, c+=256){
            int row = c >> 3, k8 = (c&7)*8;
            gload16(Sbeta + ((size_t)(z16*NN + m0 + row))*(2*NN) + j0 + k8, &sA[c*8]);
            gload16(VTh + ((size_t)(vtz*64 + row))*NN + j0 + k8, &sBh[c*8]);
            gload16(VTl + ((size_t)(vtz*64 + row))*NN + j0 + k8, &sBl[c*8]);
        }
        __syncthreads();
        #pragma unroll
        for (int kk=0; kk<2; ++kk){
            bf16x8 af = *(const bf16x8*)&sA[(wave*16 + r16)*64 + kk*32 + quad*8];
            #pragma unroll
            for (int nj=0; nj<4; ++nj){
                bf16x8 bh = *(const bf16x8*)&sBh[(nj*16 + r16)*64 + kk*32 + quad*8];
                bf16x8 bl = *(const bf16x8*)&sBl[(nj*16 + r16)*64 + kk*32 + quad*8];
                acc[nj] = __builtin_amdgcn_mfma_f32_16x16x32_bf16(af, bh, acc[nj], 0,0,0);
                acc[nj] = __builtin_amdgcn_mfma_f32_16x16x32_bf16(af, bl, acc[nj], 0,0,0);
            }
        }
    }
    #pragma unroll
    for (int nj=0;nj<4;nj++){
        #pragma unroll
        for (int r=0;r<4;r++){
            int i = m0 + wave*16 + quad*4 + r;
            int d = nj*16 + r16;
            size_t o = ((size_t)(b*NN)+i)*KK + head*64 + d;
            float v = acc[nj][r];
            x[o] = v;
            wsplit(xh, xl, o, v);
        }
    }
}

// ---------------------------------------------------------------- launch
extern "C" void kernel_launch(void* const* d_in, const int* in_sizes, int n_in,
                              void* d_out, int out_size, void* d_ws, size_t ws_size,
                              hipStream_t stream) {
    const float* mu_q    = (const float*)d_in[0];
    const float* sigma_q = (const float*)d_in[1];
    const float* phi     = (const float*)d_in[2];
    const float* gen     = (const float*)d_in[3];
    const float* mu_prior= (const float*)d_in[5];
    const float* Wq = (const float*)d_in[6];
    const float* Wk = (const float*)d_in[7];
    const float* Wv = (const float*)d_in[8];
    const float* Wo = (const float*)d_in[9];
    const float* g1 = (const float*)d_in[10];
    const float* be1= (const float*)d_in[11];
    const float* g2 = (const float*)d_in[12];
    const float* be2= (const float*)d_in[13];
    const float* W1 = (const float*)d_in[14];
    const float* bh1= (const float*)d_in[15];
    const float* W2 = (const float*)d_in[16];
    const float* bh2= (const float*)d_in[17];
    const float* lr = (const float*)d_in[18];
    float* out = (float*)d_out;

    float* w = (float*)d_ws;
    size_t off = 0;
    auto alloc = [&](size_t n){ float* p = w + off; off += (n+3)&~(size_t)3; return p; };
    auto ualloc = [&](size_t n){ return (u16*)alloc((n+1)/2); };

    float* Xb   = alloc((size_t)BN*KK);        // mu_n -> mu_g -> attn_out -> mu_n2
    float* A1b  = alloc((size_t)BN*KK);
    float* A2b  = alloc((size_t)BN*KK);        // also drive in phase E
    float* QKVb = alloc((size_t)BN*3*KK);      // QKV; later WOb / Hb / MRb
    float* SQSKb= alloc((size_t)BN*2*KK);
    float* REG  = alloc((size_t)16*NN*NN);     // X3 / Sbuf / ZH+ZL
    float* Sbuf = REG;
    u16*  X3h   = (u16*)REG;
    u16*  X3l   = X3h + (size_t)BN*3*KK;
    u16*  ZH    = (u16*)REG;
    u16*  ZL    = ZH + (size_t)BN*HIDd;
    float* Db_  = alloc((size_t)HH*BB*NN);
    float* BMb  = alloc((size_t)BB*NN*NN);
    u16* AH  = ualloc((size_t)BN*HIDd); u16* AL  = ualloc((size_t)BN*HIDd);
    u16* CFh = AH;
    u16* CFl = AH + (size_t)HH*BB*NN*128;
    u16* KSh = AL;
    u16* KSl = AL + (size_t)HH*BB*NN*128;
    u16* VTh = ualloc((size_t)HH*BB*64*NN);
    u16* VTl = ualloc((size_t)HH*BB*64*NN);
    u16* GFh = ualloc((size_t)3*KK*KK); u16* GFl = ualloc((size_t)3*KK*KK);
    u16* WQKVh= ualloc((size_t)3*KK*KK); u16* WQKVl= ualloc((size_t)3*KK*KK);
    u16* WSQKh= ualloc((size_t)2*KK*KK); u16* WSQKl= ualloc((size_t)2*KK*KK);
    u16* WoTh= ualloc((size_t)KK*KK);   u16* WoTl= ualloc((size_t)KK*KK);
    u16* W1Th= ualloc((size_t)KK*HIDd); u16* W1Tl= ualloc((size_t)KK*HIDd);
    u16* W2Th= ualloc((size_t)KK*HIDd); u16* W2Tl= ualloc((size_t)KK*HIDd);
    u16* BMh = ualloc((size_t)BB*NN*NN);u16* BMl = ualloc((size_t)BB*NN*NN);
    u16* HTh = ualloc((size_t)BB*KK*NN);u16* HTl = ualloc((size_t)BB*KK*NN);
    float* WOb = QKVb;
    float* Hb  = QKVb + (size_t)BN*KK;
    float* MRb = QKVb + 2*(size_t)BN*KK;
    float* MN2b= Xb;
    float* DRVb= A2b;

    auto gemm = [&](const u16* ah, const u16* al, const u16* bh, const u16* bl,
                    float* C, u16* chi, u16* clo, int M, int Kc, int Nc, int lda,
                    long sA, long sB, long sC, const float* bias, int act,
                    int cskip, int batch){
        dim3 g((Nc+127)/128, M/128, batch);
        gemm_mfma_k<<<g, 256, 0, stream>>>(ah, al, bh, bl, C, chi, clo,
                                           M, Kc, Nc, lda, sA, sB, sC, bias, act, cskip);
    };
    const int EW = BN*KK/4/256;   // elementwise grid

    // ---- weight prep (once) ----
    gflat_k<<<(3*KK*KK+255)/256, 256, 0, stream>>>(gen, GFh, GFl);
    {
        dim3 gq(KK/32, KK/32, 1);
        split_t_k<<<gq, 256, 0, stream>>>(Wq, WQKVh, WQKVl, KK, KK, 0L, 0L, 0);
        split_t_k<<<gq, 256, 0, stream>>>(Wk, WQKVh+(size_t)KK*KK, WQKVl+(size_t)KK*KK, KK, KK, 0L, 0L, 0);
        split_t_k<<<gq, 256, 0, stream>>>(Wv, WQKVh+2*(size_t)KK*KK, WQKVl+2*(size_t)KK*KK, KK, KK, 0L, 0L, 0);
        split_t_k<<<gq, 256, 0, stream>>>(Wo, WoTh, WoTl, KK, KK, 0L, 0L, 0);
        split_t_k<<<gq, 256, 0, stream>>>(Wq, WSQKh, WSQKl, KK, KK, 0L, 0L, 1);
        split_t_k<<<gq, 256, 0, stream>>>(Wk, WSQKh+(size_t)KK*KK, WSQKl+(size_t)KK*KK, KK, KK, 0L, 0L, 1);
        dim3 g1g(HIDd/32, KK/32, 1);
        split_t_k<<<g1g, 256, 0, stream>>>(W1, W1Th, W1Tl, KK, HIDd, 0L, 0L, 0);
        dim3 g2g(KK/32, HIDd/32, 1);
        split_t_k<<<g2g, 256, 0, stream>>>(W2, W2Th, W2Tl, HIDd, KK, 0L, 0L, 0);
    }

    // ---- phase A: LN1 + forward transport (fused phi-expand GEMMs) ----
    ln_k<<<BN, 256, 0, stream>>>(mu_q, g1, be1, Xb, 0, 0);
    expand3_k<<<EW, 256, 0, stream>>>(Xb, phi, X3h, X3l, 1.f);
    gemm(X3h, X3l, GFh, GFl, A1b, 0,0, BN, 3*KK, KK, 3*KK, 0,0,0, nullptr, 0, 0, 1);
    expand3_k<<<EW, 256, 0, stream>>>(A1b, phi, X3h, X3l, 1.f);
    gemm(X3h, X3l, GFh, GFl, A2b, 0,0, BN, 3*KK, KK, 3*KK, 0,0,0, nullptr, 0, 0, 1);
    tfinal_k<<<EW, 256, 0, stream>>>(Xb, A1b, A2b, nullptr, Xb, AH, AL);   // mu_g + split

    // ---- phase B: fused projections + attention prep ----
    gemm(AH, AL, WQKVh, WQKVl, QKVb, 0,0, BN, KK, 3*KK, KK, 0,0,0, nullptr, 0, 0, 1);
    split_k<<<(int)(((long)BN*KK+255)/256), 256, 0, stream>>>(sigma_q, AH, AL, (long)BN*KK);
    gemm(AH, AL, WSQKh, WSQKl, SQSKb, 0,0, BN, KK, 2*KK, KK, 0,0,0, nullptr, 0, 0, 1);
    prep2_k<<<BN, 512, 0, stream>>>(QKVb, SQSKb, CFh, CFl, KSh, KSl, Db_);
    {
        dim3 tg(NN/64, HH, BB);
        vtsplit_k<<<tg, 256, 0, stream>>>(QKVb, VTh, VTl);
    }

    // ---- phase C: attention, two head-groups of 4 ----
    for (int g = 0; g < 2; ++g){
        size_t cfo = (size_t)g*4*BB*NN*128;
        gemm(CFh+cfo, CFl+cfo, KSh+cfo, KSl+cfo, Sbuf, 0,0,
             NN, 128, NN, 128, (long)NN*128, (long)NN*128, (long)NN*NN,
             nullptr, 0, 1, 16);
        softmax2_k<<<BB*NN, 256, 0, stream>>>(Sbuf, Db_, BMb, BMh, BMl, g);
        dim3 pg(NN/64, 16, 1);
        pv_k<<<pg, 256, 0, stream>>>((const u16*)Sbuf, VTh, VTl, Xb, AH, AL, g);
    }

    // ---- phase D: output proj + back transport + residual + LN2 ----
    gemm(AH, AL, WoTh, WoTl, WOb, 0,0, BN, KK, KK, KK, 0,0,0, nullptr, 0, 0, 1);
    expand3_k<<<EW, 256, 0, stream>>>(WOb, phi, X3h, X3l, -1.f);
    gemm(X3h, X3l, GFh, GFl, A1b, 0,0, BN, 3*KK, KK, 3*KK, 0,0,0, nullptr, 0, 0, 1);
    expand3_k<<<EW, 256, 0, stream>>>(A1b, phi, X3h, X3l, -1.f);
    gemm(X3h, X3l, GFh, GFl, A2b, 0,0, BN, 3*KK, KK, 3*KK, 0,0,0, nullptr, 0, 0, 1);
    tfinal_k<<<EW, 256, 0, stream>>>(WOb, A1b, A2b, mu_q, MRb, 0,0);        // mu_res
    ln_k<<<BN, 256, 0, stream>>>(MRb, g2, be2, MN2b, AH, AL);               // mu_n2 + split

    // ---- phase E: 2 VFE iterations ----
    for (int it=0; it<2; ++it){
        const float* hin = (it==0) ? MN2b : Hb;
        gemm(AH, AL, W1Th, W1Tl, 0, ZH, ZL, BN, KK, HIDd, KK, 0,0,0, bh1, 1, 0, 1);
        gemm(ZH, ZL, W2Th, W2Tl, DRVb, 0,0, BN, HIDd, KK, HIDd, 0,0,0, bh2, 0, 0, 1);
        {
            dim3 tg(KK/32, NN/32, BB);
            split_t_k<<<tg, 256, 0, stream>>>(hin, HTh, HTl, NN, KK,
                                              (long)NN*KK, (long)KK*NN, 0);
        }
        {   // bmh = beta_m @ h (64-tile, K-trimmed, 512 blocks)
            dim3 bg(KK/64, NN/64, BB);
            gemm64_k<<<bg, 256, 0, stream>>>(BMh, BMl, HTh, HTl, A1b,
                                             NN, NN, KK, NN,
                                             (long)NN*NN, (long)KK*NN, (long)NN*KK);
        }
        ffn_update_k<<<EW, 256, 0, stream>>>(hin, Hb, DRVb, A1b, mu_prior, lr, AH, AL);
    }

    // ---- phase F: outputs ----
    final_k<<<EW, 256, 0, stream>>>(MRb, Hb, MN2b, out);
    copy_k<<<EW, 256, 0, stream>>>(sigma_q, out + (size_t)BN*KK, BN*KK/4);
    copy_k<<<(BN*3/4+255)/256, 256, 0, stream>>>(phi, out + 2*(size_t)BN*KK, BN*3/4);

    (void)in_sizes; (void)n_in; (void)out_size; (void)ws_size;
}

// Round 7
// 897.660 us; speedup vs baseline: 1.2027x; 1.2027x over previous
//
#include <hip/hip_runtime.h>
#include <math.h>

#define BB 4
#define NN 1024
#define KK 512
#define HH 8
#define DHh 64
#define HIDd 2048
#define BN (BB*NN)

typedef unsigned short u16;
typedef __attribute__((ext_vector_type(8))) short bf16x8;
typedef __attribute__((ext_vector_type(4))) float f32x4;

// ---------------------------------------------------------------- helpers
__device__ __forceinline__ float gelu_tanh(float x){
    float x3 = x*x*x;
    float t = tanhf(0.7978845608028654f*(x + 0.044715f*x3));
    return 0.5f*x*(1.0f+t);
}
__device__ __forceinline__ u16 f2bf(float x){
    unsigned int u = __float_as_uint(x);
    unsigned int r = (u + 0x7fffu + ((u>>16)&1u)) >> 16;
    return (u16)r;
}
__device__ __forceinline__ float bf2f(u16 b){
    return __uint_as_float(((unsigned int)b)<<16);
}
__device__ __forceinline__ void gload16(const void* g, void* l){
    __builtin_amdgcn_global_load_lds((__attribute__((address_space(1))) void*)g,
                                     (__attribute__((address_space(3))) void*)l, 16, 0, 0);
}
__device__ __forceinline__ void wsplit(u16* hi, u16* lo, size_t o, float v){
    u16 h = f2bf(v);
    hi[o] = h;
    lo[o] = f2bf(v - bf2f(h));
}

// ---------------------------------------------------------------- split conversions
__global__ __launch_bounds__(256) void split_k(const float* __restrict__ src,
                                               u16* __restrict__ hi, u16* __restrict__ lo, long n){
    long i = (long)blockIdx.x*256 + threadIdx.x;
    if (i >= n) return;
    wsplit(hi, lo, i, src[i]);
}

// src [Kc][Nc] (row-major, +batch stride sS) -> dst [Nc][Kc] hi/lo bf16 (+batch sD). square opt.
__global__ __launch_bounds__(256) void split_t_k(
    const float* __restrict__ src, u16* __restrict__ hi, u16* __restrict__ lo,
    int Kc, int Nc, long sS, long sD, int square)
{
    __shared__ float t[32][33];
    const int n0 = blockIdx.x*32, k0 = blockIdx.y*32, bz = blockIdx.z;
    const float* S = src + (long)bz*sS;
    const int tx = threadIdx.x & 31, ty = threadIdx.x >> 5;
    for (int r = ty; r < 32; r += 8){
        float v = S[(long)(k0+r)*Nc + n0+tx];
        if (square) v *= v;
        t[r][tx] = v;
    }
    __syncthreads();
    for (int r = ty; r < 32; r += 8){
        float v = t[tx][r];
        long o = (long)bz*sD + (long)(n0+r)*Kc + k0 + tx;
        wsplit(hi, lo, o, v);
    }
}

// gen (3,K,K) -> Gflat[k][g*512+l] split bf16  (B layout [512][1536])
__global__ __launch_bounds__(256) void gflat_k(const float* __restrict__ gen,
                                               u16* __restrict__ hi, u16* __restrict__ lo){
    int idx = blockIdx.x*256 + threadIdx.x;
    if (idx >= 3*KK*KK) return;
    int g = idx / (KK*KK);
    int rem = idx % (KK*KK);
    int k = rem / KK, l = rem % KK;
    wsplit(hi, lo, (size_t)k*(3*KK) + g*KK + l, gen[idx]);
}

// x3[i, g*512+l] = sign*phi[i,g]*x[i,l]  split bf16
__global__ __launch_bounds__(256) void expand3_k(
    const float* __restrict__ x, const float* __restrict__ phi,
    u16* __restrict__ xh, u16* __restrict__ xl, float sign)
{
    int idx = blockIdx.x*256 + threadIdx.x;
    if (idx >= BN*KK/4) return;
    int r = idx >> 7;
    int c4 = (idx & 127) << 2;
    const float* ph = phi + r*3;
    float4 v = *(const float4*)(x + (long)r*KK + c4);
    #pragma unroll
    for (int g=0; g<3; ++g){
        float p = sign*ph[g];
        size_t b = (size_t)r*(3*KK) + g*KK + c4;
        wsplit(xh, xl, b+0, p*v.x); wsplit(xh, xl, b+1, p*v.y);
        wsplit(xh, xl, b+2, p*v.z); wsplit(xh, xl, b+3, p*v.w);
    }
}

// ---------------------------------------------------------------- MFMA GEMM 128x128 (split bf16)
// C = A*B^T, AhBh+AhBl+AlBh.  A: [M][lda] hi/lo.  B: [Nc][Kc] hi/lo.
// cskip: 1 = skip blocks n0>m0+127 (causal S).
__global__ __launch_bounds__(256) void gemm_mfma_k(
    const u16* __restrict__ Ah, const u16* __restrict__ Al,
    const u16* __restrict__ Bh, const u16* __restrict__ Bl,
    float* __restrict__ C, u16* __restrict__ Chi, u16* __restrict__ Clo,
    int M, int Kc, int Nc, int lda,
    long sA, long sB, long sC, const float* __restrict__ bias, int act, int cskip)
{
    __shared__ u16 sAh[128*32], sAl[128*32], sBh[128*32], sBl[128*32];  // 32 KB
    const int m0 = blockIdx.y*128, n0 = blockIdx.x*128;
    if (cskip == 1 && n0 > m0 + 127) return;
    const int bz = blockIdx.z;
    const u16* gAh = Ah + (long)bz*sA;
    const u16* gAl = Al + (long)bz*sA;
    const u16* gBh = Bh + (long)bz*sB;
    const u16* gBl = Bl + (long)bz*sB;
    const int tid = threadIdx.x;
    const int wave = tid >> 6, lane = tid & 63;
    const int quad = lane >> 4, r16 = lane & 15;
    const int wm = (wave>>1)*64, wn = (wave&1)*64;

    f32x4 acc[4][4];
    #pragma unroll
    for (int i=0;i<4;i++)
        #pragma unroll
        for (int j=0;j<4;j++) acc[i][j] = (f32x4){0.f,0.f,0.f,0.f};

    for (int k0 = 0; k0 < Kc; k0 += 32){
        __syncthreads();
        #pragma unroll
        for (int half=0; half<2; ++half){
            int c = half*256 + tid;
            int row = c >> 2, kg = (c & 3)*8;
            long ga = (long)(m0+row)*lda + k0 + kg;
            long gb = (long)(n0+row)*Kc + k0 + kg;
            gload16(gAh+ga, &sAh[c*8]);
            gload16(gAl+ga, &sAl[c*8]);
            gload16(gBh+gb, &sBh[c*8]);
            gload16(gBl+gb, &sBl[c*8]);
        }
        __syncthreads();
        bf16x8 afh[4], afl[4], bfh[4], bfl[4];
        #pragma unroll
        for (int i=0;i<4;i++){
            afh[i] = *(const bf16x8*)&sAh[(wm+i*16+r16)*32 + quad*8];
            afl[i] = *(const bf16x8*)&sAl[(wm+i*16+r16)*32 + quad*8];
            bfh[i] = *(const bf16x8*)&sBh[(wn+i*16+r16)*32 + quad*8];
            bfl[i] = *(const bf16x8*)&sBl[(wn+i*16+r16)*32 + quad*8];
        }
        #pragma unroll
        for (int i=0;i<4;i++)
            #pragma unroll
            for (int j=0;j<4;j++){
                acc[i][j] = __builtin_amdgcn_mfma_f32_16x16x32_bf16(afh[i], bfh[j], acc[i][j], 0,0,0);
                acc[i][j] = __builtin_amdgcn_mfma_f32_16x16x32_bf16(afh[i], bfl[j], acc[i][j], 0,0,0);
                acc[i][j] = __builtin_amdgcn_mfma_f32_16x16x32_bf16(afl[i], bfh[j], acc[i][j], 0,0,0);
            }
    }
    #pragma unroll
    for (int i=0;i<4;i++){
        #pragma unroll
        for (int j=0;j<4;j++){
            int gc = n0 + wn + j*16 + r16;
            if (gc >= Nc) continue;
            float bv = bias ? bias[gc] : 0.f;
            #pragma unroll
            for (int r=0;r<4;r++){
                long gr = m0 + wm + i*16 + quad*4 + r;
                float v = acc[i][j][r] + bv;
                if (act) v = gelu_tanh(v);
                long o = (long)bz*sC + gr*Nc + gc;
                if (C) C[o] = v;
                if (Chi) wsplit(Chi, Clo, o, v);
            }
        }
    }
}

// ---------------------------------------------------------------- MFMA GEMM 64x64 tile (high-occupancy)
// C = A*B^T. 4 waves, wave w owns rows w*16..w*16+15. ktrim: K trimmed to m0+64 (lower-tri A).
__global__ __launch_bounds__(256) void gemm64_k(
    const u16* __restrict__ Ah, const u16* __restrict__ Al,
    const u16* __restrict__ Bh, const u16* __restrict__ Bl,
    float* __restrict__ C, u16* __restrict__ Chi, u16* __restrict__ Clo,
    int M, int Kc, int Nc, int lda,
    long sA, long sB, long sC, const float* __restrict__ bias, int act, int ktrim)
{
    __shared__ u16 sAh[64*32], sAl[64*32], sBh[64*32], sBl[64*32];  // 16 KB
    const int m0 = blockIdx.y*64, n0 = blockIdx.x*64;
    const int bz = blockIdx.z;
    const u16* gAh = Ah + (long)bz*sA;
    const u16* gAl = Al + (long)bz*sA;
    const u16* gBh = Bh + (long)bz*sB;
    const u16* gBl = Bl + (long)bz*sB;
    const int tid = threadIdx.x;
    const int wave = tid >> 6, lane = tid & 63;
    const int quad = lane >> 4, r16 = lane & 15;
    const int wr = wave*16;
    const int kend = ktrim ? min(Kc, m0 + 64) : Kc;

    f32x4 acc[4];
    #pragma unroll
    for (int j=0;j<4;j++) acc[j] = (f32x4){0.f,0.f,0.f,0.f};

    for (int k0 = 0; k0 < kend; k0 += 32){
        __syncthreads();
        {
            int row = tid >> 2, kg = (tid & 3)*8;
            long ga = (long)(m0+row)*lda + k0 + kg;
            long gb = (long)(n0+row)*Kc + k0 + kg;
            gload16(gAh+ga, &sAh[tid*8]);
            gload16(gAl+ga, &sAl[tid*8]);
            gload16(gBh+gb, &sBh[tid*8]);
            gload16(gBl+gb, &sBl[tid*8]);
        }
        __syncthreads();
        bf16x8 afh = *(const bf16x8*)&sAh[(wr+r16)*32 + quad*8];
        bf16x8 afl = *(const bf16x8*)&sAl[(wr+r16)*32 + quad*8];
        #pragma unroll
        for (int j=0;j<4;j++){
            bf16x8 bh = *(const bf16x8*)&sBh[(j*16+r16)*32 + quad*8];
            bf16x8 bl = *(const bf16x8*)&sBl[(j*16+r16)*32 + quad*8];
            acc[j] = __builtin_amdgcn_mfma_f32_16x16x32_bf16(afh, bh, acc[j], 0,0,0);
            acc[j] = __builtin_amdgcn_mfma_f32_16x16x32_bf16(afh, bl, acc[j], 0,0,0);
            acc[j] = __builtin_amdgcn_mfma_f32_16x16x32_bf16(afl, bh, acc[j], 0,0,0);
        }
    }
    #pragma unroll
    for (int j=0;j<4;j++){
        int gc = n0 + j*16 + r16;
        float bv = bias ? bias[gc] : 0.f;
        #pragma unroll
        for (int r=0;r<4;r++){
            long gr = m0 + wr + quad*4 + r;
            float v = acc[j][r] + bv;
            if (act) v = gelu_tanh(v);
            long o = (long)bz*sC + gr*Nc + gc;
            if (C) C[o] = v;
            if (Chi) wsplit(Chi, Clo, o, v);
        }
    }
}

// ---------------------------------------------------------------- LayerNorm (rows of 512), optional split out
__global__ __launch_bounds__(256) void ln_k(
    const float* __restrict__ x, const float* __restrict__ g,
    const float* __restrict__ be, float* __restrict__ y,
    u16* __restrict__ yh, u16* __restrict__ yl)
{
    __shared__ float sh[8];
    const int r = blockIdx.x, tid = threadIdx.x;
    const float* xr = x + (long)r*KK;
    float2 v = *(const float2*)(xr + tid*2);
    float s = v.x+v.y, s2 = v.x*v.x+v.y*v.y;
    #pragma unroll
    for (int o=32;o>0;o>>=1){ s += __shfl_down(s,o); s2 += __shfl_down(s2,o); }
    if ((tid&63)==0){ sh[tid>>6]=s; sh[4+(tid>>6)]=s2; }
    __syncthreads();
    s  = sh[0]+sh[1]+sh[2]+sh[3];
    s2 = sh[4]+sh[5]+sh[6]+sh[7];
    const float mean = s*(1.f/KK);
    const float var  = s2*(1.f/KK) - mean*mean;
    const float rs = rsqrtf(var + 1e-5f);
    float2 gg = *(const float2*)(g + tid*2);
    float2 bb = *(const float2*)(be + tid*2);
    float ox = (v.x-mean)*rs*gg.x + bb.x;
    float oy = (v.y-mean)*rs*gg.y + bb.y;
    long o = (long)r*KK + tid*2;
    *(float2*)(y + o) = make_float2(ox, oy);
    if (yh){ wsplit(yh, yl, o, ox); wsplit(yh, yl, o+1, oy); }
}

// ---------------------------------------------------------------- elementwise kernels
__global__ void tfinal_k(const float* __restrict__ x, const float* __restrict__ a1,
                         const float* __restrict__ a2, const float* __restrict__ res,
                         float* __restrict__ out, u16* __restrict__ oh, u16* __restrict__ ol){
    int i = blockIdx.x*256 + threadIdx.x;
    if (i >= BN*KK/4) return;
    float4 xv = ((const float4*)x)[i];
    float4 v1 = ((const float4*)a1)[i];
    float4 v2 = ((const float4*)a2)[i];
    float4 o;
    o.x = xv.x + v1.x + 0.5f*v2.x;
    o.y = xv.y + v1.y + 0.5f*v2.y;
    o.z = xv.z + v1.z + 0.5f*v2.z;
    o.w = xv.w + v1.w + 0.5f*v2.w;
    if (res){ float4 rv = ((const float4*)res)[i]; o.x+=rv.x; o.y+=rv.y; o.z+=rv.z; o.w+=rv.w; }
    ((float4*)out)[i] = o;
    if (oh){
        long ob = (long)i*4;
        wsplit(oh, ol, ob+0, o.x); wsplit(oh, ol, ob+1, o.y);
        wsplit(oh, ol, ob+2, o.z); wsplit(oh, ol, ob+3, o.w);
    }
}
__global__ void copy_k(const float* __restrict__ s, float* __restrict__ d, int n4){
    int i = blockIdx.x*256 + threadIdx.x;
    if (i < n4) ((float4*)d)[i] = ((const float4*)s)[i];
}
__global__ void final_k(const float* __restrict__ a, const float* __restrict__ b,
                        const float* __restrict__ c, float* __restrict__ out){
    int i = blockIdx.x*256 + threadIdx.x;
    if (i >= BN*KK/4) return;
    float4 av = ((const float4*)a)[i], bv = ((const float4*)b)[i], cv = ((const float4*)c)[i];
    float4 o;
    o.x = av.x + bv.x - cv.x; o.y = av.y + bv.y - cv.y;
    o.z = av.z + bv.z - cv.z; o.w = av.w + bv.w - cv.w;
    ((float4*)out)[i] = o;
}
__global__ void ffn_update_k(const float* __restrict__ hin, float* __restrict__ hout,
                             const float* __restrict__ drive, const float* __restrict__ bmh,
                             const float* __restrict__ mup, const float* __restrict__ lr,
                             u16* __restrict__ hh, u16* __restrict__ hl){
    int i = blockIdx.x*256 + threadIdx.x;
    if (i >= BN*KK/4) return;
    const float lrv = *lr;
    float4 hv = ((const float4*)hin)[i];
    float4 dv = ((const float4*)drive)[i];
    float4 bv = ((const float4*)bmh)[i];
    float4 pv = ((const float4*)mup)[i];
    float4 o;
    o.x = hv.x + lrv*(dv.x - (1e-3f*(hv.x-pv.x) + 1.0f*(hv.x-bv.x)));
    o.y = hv.y + lrv*(dv.y - (1e-3f*(hv.y-pv.y) + 1.0f*(hv.y-bv.y)));
    o.z = hv.z + lrv*(dv.z - (1e-3f*(hv.z-pv.z) + 1.0f*(hv.z-bv.z)));
    o.w = hv.w + lrv*(dv.w - (1e-3f*(hv.w-pv.w) + 1.0f*(hv.w-bv.w)));
    ((float4*)hout)[i] = o;
    long ob = (long)i*4;
    wsplit(hh, hl, ob+0, o.x); wsplit(hh, hl, ob+1, o.y);
    wsplit(hh, hl, ob+2, o.z); wsplit(hh, hl, ob+3, o.w);
}

// ---------------------------------------------------------------- attention prep (QKV stride 1536, SQSK stride 1024)
__global__ __launch_bounds__(512) void prep2_k(
    const float* __restrict__ QKV, const float* __restrict__ SQSK,
    u16* __restrict__ CFh, u16* __restrict__ CFl,
    u16* __restrict__ KSh, u16* __restrict__ KSl, float* __restrict__ dvec)
{
    const int bn = blockIdx.x;
    const int b = bn / NN, n = bn % NN;
    const int h = threadIdx.x >> 6, d = threadIdx.x & 63;
    float q  = QKV[(size_t)bn*1536 + h*DHh + d];
    float k  = QKV[(size_t)bn*1536 + KK + h*DHh + d];
    float sq = SQSK[(size_t)bn*1024 + h*DHh + d] + 1e-8f;
    float sk = SQSK[(size_t)bn*1024 + KK + h*DHh + d] + 1e-8f;
    float inv = 1.f/sq;
    float nqi = -2.f*q*inv;
    float skk = sk + k*k;
    const size_t base = ((size_t)(h*BB + b)*NN + n)*128;
    wsplit(CFh, CFl, base+d,    inv);
    wsplit(CFh, CFl, base+64+d, nqi);
    wsplit(KSh, KSl, base+d,    skk);
    wsplit(KSh, KSl, base+64+d, k);
    float dv = __logf(sk);
    #pragma unroll
    for (int o=32;o>0;o>>=1) dv += __shfl_down(dv,o);
    if (d==0) dvec[((size_t)h*BB + b)*NN + n] = dv;
}

// ---------------------------------------------------------------- V transpose+split
__global__ __launch_bounds__(256) void vtsplit_k(
    const float* __restrict__ QKV, u16* __restrict__ VTh, u16* __restrict__ VTl)
{
    __shared__ float t[64][65];
    const int n0 = blockIdx.x * 64;
    const int h = blockIdx.y, b = blockIdx.z;
    const int tid = threadIdx.x;
    const int c4 = (tid & 15) * 4;
    const int r0 = tid >> 4;
    for (int rr = r0; rr < 64; rr += 16){
        float4 v = *(const float4*)(QKV + (size_t)(b*NN + n0 + rr)*1536 + 1024 + h*DHh + c4);
        t[c4+0][rr] = v.x; t[c4+1][rr] = v.y; t[c4+2][rr] = v.z; t[c4+3][rr] = v.w;
    }
    __syncthreads();
    for (int dd = r0; dd < 64; dd += 16){
        size_t base = ((size_t)(h*BB + b)*64 + dd)*NN + n0 + c4;
        #pragma unroll
        for (int q=0;q<4;q++) wsplit(VTh, VTl, base+q, t[dd][c4+q]);
    }
}

// ---------------------------------------------------------------- softmax for a head-group of 4
__global__ __launch_bounds__(256) void softmax2_k(
    float* __restrict__ S, const float* __restrict__ dvec,
    float* __restrict__ betam, u16* __restrict__ BMh, u16* __restrict__ BMl, int g)
{
    __shared__ float s_sc[NN];
    __shared__ float s_bm[NN];
    __shared__ float s_red[4];
    const int tid = threadIdx.x;
    const int b = blockIdx.x / NN, i = blockIdx.x % NN;
    const int L = i + 1;
    for (int j=tid;j<NN;j+=256) s_bm[j]=0.f;
    for (int hg=0; hg<4; ++hg){
        const int z = hg*BB + b;
        float* row = S + ((long)z*NN + i)*NN;
        const float* dp = dvec + ((size_t)(g*4+hg)*BB + b)*NN;
        float lm = -3.0e38f;
        for (int j=tid;j<L;j+=256){
            float sc = -0.5f*row[j] + 0.5f*dp[j];
            s_sc[j] = sc;
            lm = fmaxf(lm, sc);
        }
        #pragma unroll
        for (int o=32;o>0;o>>=1) lm = fmaxf(lm, __shfl_xor(lm, o));
        __syncthreads();
        if ((tid&63)==0) s_red[tid>>6] = lm;
        __syncthreads();
        const float mx = fmaxf(fmaxf(s_red[0],s_red[1]), fmaxf(s_red[2],s_red[3]));
        float ps = 0.f;
        for (int j=tid;j<L;j+=256){
            float e = __expf(s_sc[j]-mx);
            s_sc[j] = e;
            ps += e;
        }
        #pragma unroll
        for (int o=32;o>0;o>>=1) ps += __shfl_xor(ps, o);
        __syncthreads();
        if ((tid&63)==0) s_red[tid>>6] = ps;
        __syncthreads();
        const float isum = 1.f/(s_red[0]+s_red[1]+s_red[2]+s_red[3]);
        u16* brow = (u16*)row;
        for (int j=tid;j<NN;j+=256){
            if (j < L){
                float w = s_sc[j]*isum;
                brow[j] = f2bf(w);
                s_bm[j] += 0.125f*w;
            } else {
                brow[j] = 0;
            }
        }
        __syncthreads();
    }
    const long bmrow = ((long)b*NN + i)*NN;
    if (g == 0){
        for (int j=tid;j<NN;j+=256) betam[bmrow+j] = s_bm[j];
    } else {
        for (int j=tid;j<NN;j+=256){
            float v = betam[bmrow+j] + s_bm[j];
            wsplit(BMh, BMl, bmrow+j, v);
        }
    }
}

// ---------------------------------------------------------------- PV: out[i,d] = sum_j beta[i,j] V[j,d]
__global__ __launch_bounds__(256) void pv_k(
    const u16* __restrict__ Sbeta,
    const u16* __restrict__ VTh, const u16* __restrict__ VTl,
    float* __restrict__ x, u16* __restrict__ xh, u16* __restrict__ xl, int g)
{
    __shared__ u16 sA[64*64];
    __shared__ u16 sBh[64*64];
    __shared__ u16 sBl[64*64];
    const int m0 = blockIdx.x*64;
    const int z16 = blockIdx.y;
    const int b = z16 & 3, hg = z16 >> 2;
    const int head = g*4 + hg;
    const int vtz = head*BB + b;
    const int tid = threadIdx.x;
    const int wave = tid>>6, lane = tid&63;
    const int quad = lane>>4, r16 = lane&15;
    f32x4 acc[4];
    #pragma unroll
    for (int j=0;j<4;j++) acc[j]=(f32x4){0.f,0.f,0.f,0.f};
    const int jmax = m0 + 64;
    for (int j0 = 0; j0 < jmax; j0 += 64){
        __syncthreads();
        int c = tid;
        #pragma unroll
        for (int rep=0; rep<2; ++rep, c+=256){
            int row = c >> 3, k8 = (c&7)*8;
            gload16(Sbeta + ((size_t)(z16*NN + m0 + row))*(2*NN) + j0 + k8, &sA[c*8]);
            gload16(VTh + ((size_t)(vtz*64 + row))*NN + j0 + k8, &sBh[c*8]);
            gload16(VTl + ((size_t)(vtz*64 + row))*NN + j0 + k8, &sBl[c*8]);
        }
        __syncthreads();
        #pragma unroll
        for (int kk=0; kk<2; ++kk){
            bf16x8 af = *(const bf16x8*)&sA[(wave*16 + r16)*64 + kk*32 + quad*8];
            #pragma unroll
            for (int nj=0; nj<4; ++nj){
                bf16x8 bh = *(const bf16x8*)&sBh[(nj*16 + r16)*64 + kk*32 + quad*8];
                bf16x8 bl = *(const bf16x8*)&sBl[(nj*16 + r16)*64 + kk*32 + quad*8];
                acc[nj] = __builtin_amdgcn_mfma_f32_16x16x32_bf16(af, bh, acc[nj], 0,0,0);
                acc[nj] = __builtin_amdgcn_mfma_f32_16x16x32_bf16(af, bl, acc[nj], 0,0,0);
            }
        }
    }
    #pragma unroll
    for (int nj=0;nj<4;nj++){
        #pragma unroll
        for (int r=0;r<4;r++){
            int i = m0 + wave*16 + quad*4 + r;
            int d = nj*16 + r16;
            size_t o = ((size_t)(b*NN)+i)*KK + head*64 + d;
            float v = acc[nj][r];
            x[o] = v;
            wsplit(xh, xl, o, v);
        }
    }
}

// ---------------------------------------------------------------- launch
extern "C" void kernel_launch(void* const* d_in, const int* in_sizes, int n_in,
                              void* d_out, int out_size, void* d_ws, size_t ws_size,
                              hipStream_t stream) {
    const float* mu_q    = (const float*)d_in[0];
    const float* sigma_q = (const float*)d_in[1];
    const float* phi     = (const float*)d_in[2];
    const float* gen     = (const float*)d_in[3];
    const float* mu_prior= (const float*)d_in[5];
    const float* Wq = (const float*)d_in[6];
    const float* Wk = (const float*)d_in[7];
    const float* Wv = (const float*)d_in[8];
    const float* Wo = (const float*)d_in[9];
    const float* g1 = (const float*)d_in[10];
    const float* be1= (const float*)d_in[11];
    const float* g2 = (const float*)d_in[12];
    const float* be2= (const float*)d_in[13];
    const float* W1 = (const float*)d_in[14];
    const float* bh1= (const float*)d_in[15];
    const float* W2 = (const float*)d_in[16];
    const float* bh2= (const float*)d_in[17];
    const float* lr = (const float*)d_in[18];
    float* out = (float*)d_out;

    float* w = (float*)d_ws;
    size_t off = 0;
    auto alloc = [&](size_t n){ float* p = w + off; off += (n+3)&~(size_t)3; return p; };
    auto ualloc = [&](size_t n){ return (u16*)alloc((n+1)/2); };

    float* Xb   = alloc((size_t)BN*KK);        // mu_n -> mu_g -> attn_out -> mu_n2
    float* A1b  = alloc((size_t)BN*KK);
    float* A2b  = alloc((size_t)BN*KK);        // also drive in phase E
    float* QKVb = alloc((size_t)BN*3*KK);      // QKV; later WOb / Hb / MRb
    float* SQSKb= alloc((size_t)BN*2*KK);
    float* REG  = alloc((size_t)16*NN*NN);     // X3 / Sbuf / ZH+ZL
    float* Sbuf = REG;
    u16*  X3h   = (u16*)REG;
    u16*  X3l   = X3h + (size_t)BN*3*KK;
    u16*  ZH    = (u16*)REG;
    u16*  ZL    = ZH + (size_t)BN*HIDd;
    float* Db_  = alloc((size_t)HH*BB*NN);
    float* BMb  = alloc((size_t)BB*NN*NN);
    u16* AH  = ualloc((size_t)BN*HIDd); u16* AL  = ualloc((size_t)BN*HIDd);
    u16* CFh = AH;
    u16* CFl = AH + (size_t)HH*BB*NN*128;
    u16* KSh = AL;
    u16* KSl = AL + (size_t)HH*BB*NN*128;
    u16* VTh = ualloc((size_t)HH*BB*64*NN);
    u16* VTl = ualloc((size_t)HH*BB*64*NN);
    u16* GFh = ualloc((size_t)3*KK*KK); u16* GFl = ualloc((size_t)3*KK*KK);
    u16* WQKVh= ualloc((size_t)3*KK*KK); u16* WQKVl= ualloc((size_t)3*KK*KK);
    u16* WSQKh= ualloc((size_t)2*KK*KK); u16* WSQKl= ualloc((size_t)2*KK*KK);
    u16* WoTh= ualloc((size_t)KK*KK);   u16* WoTl= ualloc((size_t)KK*KK);
    u16* W1Th= ualloc((size_t)KK*HIDd); u16* W1Tl= ualloc((size_t)KK*HIDd);
    u16* W2Th= ualloc((size_t)KK*HIDd); u16* W2Tl= ualloc((size_t)KK*HIDd);
    u16* BMh = ualloc((size_t)BB*NN*NN);u16* BMl = ualloc((size_t)BB*NN*NN);
    u16* HTh = ualloc((size_t)BB*KK*NN);u16* HTl = ualloc((size_t)BB*KK*NN);
    float* WOb = QKVb;
    float* Hb  = QKVb + (size_t)BN*KK;
    float* MRb = QKVb + 2*(size_t)BN*KK;
    float* MN2b= Xb;
    float* DRVb= A2b;

    auto gemm = [&](const u16* ah, const u16* al, const u16* bh, const u16* bl,
                    float* C, u16* chi, u16* clo, int M, int Kc, int Nc, int lda,
                    long sA, long sB, long sC, const float* bias, int act,
                    int cskip, int batch){
        dim3 g((Nc+127)/128, M/128, batch);
        gemm_mfma_k<<<g, 256, 0, stream>>>(ah, al, bh, bl, C, chi, clo,
                                           M, Kc, Nc, lda, sA, sB, sC, bias, act, cskip);
    };
    auto gemm64 = [&](const u16* ah, const u16* al, const u16* bh, const u16* bl,
                      float* C, u16* chi, u16* clo, int M, int Kc, int Nc, int lda,
                      long sA, long sB, long sC, const float* bias, int act,
                      int ktrim, int batch){
        dim3 g(Nc/64, M/64, batch);
        gemm64_k<<<g, 256, 0, stream>>>(ah, al, bh, bl, C, chi, clo,
                                        M, Kc, Nc, lda, sA, sB, sC, bias, act, ktrim);
    };
    const int EW = BN*KK/4/256;   // elementwise grid

    // ---- weight prep (once) ----
    gflat_k<<<(3*KK*KK+255)/256, 256, 0, stream>>>(gen, GFh, GFl);
    {
        dim3 gq(KK/32, KK/32, 1);
        split_t_k<<<gq, 256, 0, stream>>>(Wq, WQKVh, WQKVl, KK, KK, 0L, 0L, 0);
        split_t_k<<<gq, 256, 0, stream>>>(Wk, WQKVh+(size_t)KK*KK, WQKVl+(size_t)KK*KK, KK, KK, 0L, 0L, 0);
        split_t_k<<<gq, 256, 0, stream>>>(Wv, WQKVh+2*(size_t)KK*KK, WQKVl+2*(size_t)KK*KK, KK, KK, 0L, 0L, 0);
        split_t_k<<<gq, 256, 0, stream>>>(Wo, WoTh, WoTl, KK, KK, 0L, 0L, 0);
        split_t_k<<<gq, 256, 0, stream>>>(Wq, WSQKh, WSQKl, KK, KK, 0L, 0L, 1);
        split_t_k<<<gq, 256, 0, stream>>>(Wk, WSQKh+(size_t)KK*KK, WSQKl+(size_t)KK*KK, KK, KK, 0L, 0L, 1);
        dim3 g1g(HIDd/32, KK/32, 1);
        split_t_k<<<g1g, 256, 0, stream>>>(W1, W1Th, W1Tl, KK, HIDd, 0L, 0L, 0);
        dim3 g2g(KK/32, HIDd/32, 1);
        split_t_k<<<g2g, 256, 0, stream>>>(W2, W2Th, W2Tl, HIDd, KK, 0L, 0L, 0);
    }

    // ---- phase A: LN1 + forward transport (fused phi-expand, 64-tile GEMMs) ----
    ln_k<<<BN, 256, 0, stream>>>(mu_q, g1, be1, Xb, 0, 0);
    expand3_k<<<EW, 256, 0, stream>>>(Xb, phi, X3h, X3l, 1.f);
    gemm64(X3h, X3l, GFh, GFl, A1b, 0,0, BN, 3*KK, KK, 3*KK, 0,0,0, nullptr, 0, 0, 1);
    expand3_k<<<EW, 256, 0, stream>>>(A1b, phi, X3h, X3l, 1.f);
    gemm64(X3h, X3l, GFh, GFl, A2b, 0,0, BN, 3*KK, KK, 3*KK, 0,0,0, nullptr, 0, 0, 1);
    tfinal_k<<<EW, 256, 0, stream>>>(Xb, A1b, A2b, nullptr, Xb, AH, AL);   // mu_g + split

    // ---- phase B: fused projections + attention prep ----
    gemm(AH, AL, WQKVh, WQKVl, QKVb, 0,0, BN, KK, 3*KK, KK, 0,0,0, nullptr, 0, 0, 1);
    split_k<<<(int)(((long)BN*KK+255)/256), 256, 0, stream>>>(sigma_q, AH, AL, (long)BN*KK);
    gemm(AH, AL, WSQKh, WSQKl, SQSKb, 0,0, BN, KK, 2*KK, KK, 0,0,0, nullptr, 0, 0, 1);
    prep2_k<<<BN, 512, 0, stream>>>(QKVb, SQSKb, CFh, CFl, KSh, KSl, Db_);
    {
        dim3 tg(NN/64, HH, BB);
        vtsplit_k<<<tg, 256, 0, stream>>>(QKVb, VTh, VTl);
    }

    // ---- phase C: attention, two head-groups of 4 ----
    for (int g = 0; g < 2; ++g){
        size_t cfo = (size_t)g*4*BB*NN*128;
        gemm(CFh+cfo, CFl+cfo, KSh+cfo, KSl+cfo, Sbuf, 0,0,
             NN, 128, NN, 128, (long)NN*128, (long)NN*128, (long)NN*NN,
             nullptr, 0, 1, 16);
        softmax2_k<<<BB*NN, 256, 0, stream>>>(Sbuf, Db_, BMb, BMh, BMl, g);
        dim3 pg(NN/64, 16, 1);
        pv_k<<<pg, 256, 0, stream>>>((const u16*)Sbuf, VTh, VTl, Xb, AH, AL, g);
    }

    // ---- phase D: output proj + back transport + residual + LN2 ----
    gemm64(AH, AL, WoTh, WoTl, WOb, 0,0, BN, KK, KK, KK, 0,0,0, nullptr, 0, 0, 1);
    expand3_k<<<EW, 256, 0, stream>>>(WOb, phi, X3h, X3l, -1.f);
    gemm64(X3h, X3l, GFh, GFl, A1b, 0,0, BN, 3*KK, KK, 3*KK, 0,0,0, nullptr, 0, 0, 1);
    expand3_k<<<EW, 256, 0, stream>>>(A1b, phi, X3h, X3l, -1.f);
    gemm64(X3h, X3l, GFh, GFl, A2b, 0,0, BN, 3*KK, KK, 3*KK, 0,0,0, nullptr, 0, 0, 1);
    tfinal_k<<<EW, 256, 0, stream>>>(WOb, A1b, A2b, mu_q, MRb, 0,0);        // mu_res
    ln_k<<<BN, 256, 0, stream>>>(MRb, g2, be2, MN2b, AH, AL);               // mu_n2 + split

    // ---- phase E: 2 VFE iterations ----
    for (int it=0; it<2; ++it){
        const float* hin = (it==0) ? MN2b : Hb;
        gemm(AH, AL, W1Th, W1Tl, 0, ZH, ZL, BN, KK, HIDd, KK, 0,0,0, bh1, 1, 0, 1);
        gemm64(ZH, ZL, W2Th, W2Tl, DRVb, 0,0, BN, HIDd, KK, HIDd, 0,0,0, bh2, 0, 0, 1);
        {
            dim3 tg(KK/32, NN/32, BB);
            split_t_k<<<tg, 256, 0, stream>>>(hin, HTh, HTl, NN, KK,
                                              (long)NN*KK, (long)KK*NN, 0);
        }
        {   // bmh = beta_m @ h (64-tile, K-trimmed, 512 blocks)
            dim3 bg(KK/64, NN/64, BB);
            gemm64_k<<<bg, 256, 0, stream>>>(BMh, BMl, HTh, HTl, A1b, 0,0,
                                             NN, NN, KK, NN,
                                             (long)NN*NN, (long)KK*NN, (long)NN*KK,
                                             nullptr, 0, 1);
        }
        ffn_update_k<<<EW, 256, 0, stream>>>(hin, Hb, DRVb, A1b, mu_prior, lr, AH, AL);
    }

    // ---- phase F: outputs ----
    final_k<<<EW, 256, 0, stream>>>(MRb, Hb, MN2b, out);
    copy_k<<<EW, 256, 0, stream>>>(sigma_q, out + (size_t)BN*KK, BN*KK/4);
    copy_k<<<(BN*3/4+255)/256, 256, 0, stream>>>(phi, out + 2*(size_t)BN*KK, BN*3/4);

    (void)in_sizes; (void)n_in; (void)out_size; (void)ws_size;
}

// Round 8
// 775.051 us; speedup vs baseline: 1.3929x; 1.1582x over previous
//
#include <hip/hip_runtime.h>
#include <math.h>

#define BB 4
#define NN 1024
#define KK 512
#define HH 8
#define DHh 64
#define HIDd 2048
#define BN (BB*NN)

typedef unsigned short u16;
typedef __attribute__((ext_vector_type(8))) short bf16x8;
typedef __attribute__((ext_vector_type(4))) float f32x4;

// ---------------------------------------------------------------- helpers
__device__ __forceinline__ float gelu_tanh(float x){
    float x3 = x*x*x;
    float t = tanhf(0.7978845608028654f*(x + 0.044715f*x3));
    return 0.5f*x*(1.0f+t);
}
__device__ __forceinline__ u16 f2bf(float x){
    unsigned int u = __float_as_uint(x);
    unsigned int r = (u + 0x7fffu + ((u>>16)&1u)) >> 16;
    return (u16)r;
}
__device__ __forceinline__ float bf2f(u16 b){
    return __uint_as_float(((unsigned int)b)<<16);
}
__device__ __forceinline__ void gload16(const void* g, void* l){
    __builtin_amdgcn_global_load_lds((__attribute__((address_space(1))) void*)g,
                                     (__attribute__((address_space(3))) void*)l, 16, 0, 0);
}
__device__ __forceinline__ void wsplit(u16* hi, u16* lo, size_t o, float v){
    u16 h = f2bf(v);
    hi[o] = h;
    if (lo) lo[o] = f2bf(v - bf2f(h));
}

// ---------------------------------------------------------------- split conversions
__global__ __launch_bounds__(256) void split_k(const float* __restrict__ src,
                                               u16* __restrict__ hi, u16* __restrict__ lo, long n){
    long i = (long)blockIdx.x*256 + threadIdx.x;
    if (i >= n) return;
    wsplit(hi, lo, i, src[i]);
}

// src [Kc][Nc] (row-major, +batch stride sS) -> dst [Nc][Kc] hi[/lo] bf16. square opt.
__global__ __launch_bounds__(256) void split_t_k(
    const float* __restrict__ src, u16* __restrict__ hi, u16* __restrict__ lo,
    int Kc, int Nc, long sS, long sD, int square)
{
    __shared__ float t[32][33];
    const int n0 = blockIdx.x*32, k0 = blockIdx.y*32, bz = blockIdx.z;
    const float* S = src + (long)bz*sS;
    const int tx = threadIdx.x & 31, ty = threadIdx.x >> 5;
    for (int r = ty; r < 32; r += 8){
        float v = S[(long)(k0+r)*Nc + n0+tx];
        if (square) v *= v;
        t[r][tx] = v;
    }
    __syncthreads();
    for (int r = ty; r < 32; r += 8){
        float v = t[tx][r];
        long o = (long)bz*sD + (long)(n0+r)*Kc + k0 + tx;
        wsplit(hi, lo, o, v);
    }
}

// gen (3,K,K) -> Gflat[k][g*512+l] bf16 hi only
__global__ __launch_bounds__(256) void gflat_k(const float* __restrict__ gen,
                                               u16* __restrict__ hi){
    int idx = blockIdx.x*256 + threadIdx.x;
    if (idx >= 3*KK*KK) return;
    int g = idx / (KK*KK);
    int rem = idx % (KK*KK);
    int k = rem / KK, l = rem % KK;
    hi[(size_t)k*(3*KK) + g*KK + l] = f2bf(gen[idx]);
}

// x3[i, g*512+l] = sign*phi[i,g]*x[i,l]  bf16 hi only
__global__ __launch_bounds__(256) void expand3_k(
    const float* __restrict__ x, const float* __restrict__ phi,
    u16* __restrict__ xh, float sign)
{
    int idx = blockIdx.x*256 + threadIdx.x;
    if (idx >= BN*KK/4) return;
    int r = idx >> 7;
    int c4 = (idx & 127) << 2;
    const float* ph = phi + r*3;
    float4 v = *(const float4*)(x + (long)r*KK + c4);
    #pragma unroll
    for (int g=0; g<3; ++g){
        float p = sign*ph[g];
        size_t b = (size_t)r*(3*KK) + g*KK + c4;
        xh[b+0]=f2bf(p*v.x); xh[b+1]=f2bf(p*v.y);
        xh[b+2]=f2bf(p*v.z); xh[b+3]=f2bf(p*v.w);
    }
}

// ---------------------------------------------------------------- MFMA GEMM 128x128, grid: (M/128, N/128, batch)  [m on x => XCD A-locality]
// prods: 3=AhBh+AhBl+AlBh, 2=AhBh+AhBl, 1=AhBh.  cskip: skip n0>m0+127.
__global__ __launch_bounds__(256) void gemm_mfma_k(
    const u16* __restrict__ Ah, const u16* __restrict__ Al,
    const u16* __restrict__ Bh, const u16* __restrict__ Bl,
    float* __restrict__ C, u16* __restrict__ Chi, u16* __restrict__ Clo,
    int M, int Kc, int Nc, int lda,
    long sA, long sB, long sC, const float* __restrict__ bias, int act,
    int cskip, int prods)
{
    __shared__ u16 sAh[128*32], sAl[128*32], sBh[128*32], sBl[128*32];
    const int m0 = blockIdx.x*128, n0 = blockIdx.y*128;
    if (cskip == 1 && n0 > m0 + 127) return;
    const int bz = blockIdx.z;
    const u16* gAh = Ah + (long)bz*sA;
    const u16* gAl = Al + (long)bz*sA;
    const u16* gBh = Bh + (long)bz*sB;
    const u16* gBl = Bl + (long)bz*sB;
    const int tid = threadIdx.x;
    const int wave = tid >> 6, lane = tid & 63;
    const int quad = lane >> 4, r16 = lane & 15;
    const int wm = (wave>>1)*64, wn = (wave&1)*64;

    f32x4 acc[4][4];
    #pragma unroll
    for (int i=0;i<4;i++)
        #pragma unroll
        for (int j=0;j<4;j++) acc[i][j] = (f32x4){0.f,0.f,0.f,0.f};

    for (int k0 = 0; k0 < Kc; k0 += 32){
        __syncthreads();
        #pragma unroll
        for (int half=0; half<2; ++half){
            int c = half*256 + tid;
            int row = c >> 2, kg = (c & 3)*8;
            long ga = (long)(m0+row)*lda + k0 + kg;
            long gb = (long)(n0+row)*Kc + k0 + kg;
            gload16(gAh+ga, &sAh[c*8]);
            if (prods == 3) gload16(gAl+ga, &sAl[c*8]);
            gload16(gBh+gb, &sBh[c*8]);
            if (prods >= 2) gload16(gBl+gb, &sBl[c*8]);
        }
        __syncthreads();
        bf16x8 afh[4], afl[4], bfh[4], bfl[4];
        #pragma unroll
        for (int i=0;i<4;i++){
            afh[i] = *(const bf16x8*)&sAh[(wm+i*16+r16)*32 + quad*8];
            bfh[i] = *(const bf16x8*)&sBh[(wn+i*16+r16)*32 + quad*8];
        }
        if (prods >= 2)
            #pragma unroll
            for (int i=0;i<4;i++) bfl[i] = *(const bf16x8*)&sBl[(wn+i*16+r16)*32 + quad*8];
        if (prods == 3)
            #pragma unroll
            for (int i=0;i<4;i++) afl[i] = *(const bf16x8*)&sAl[(wm+i*16+r16)*32 + quad*8];
        #pragma unroll
        for (int i=0;i<4;i++)
            #pragma unroll
            for (int j=0;j<4;j++){
                acc[i][j] = __builtin_amdgcn_mfma_f32_16x16x32_bf16(afh[i], bfh[j], acc[i][j], 0,0,0);
                if (prods >= 2)
                    acc[i][j] = __builtin_amdgcn_mfma_f32_16x16x32_bf16(afh[i], bfl[j], acc[i][j], 0,0,0);
                if (prods == 3)
                    acc[i][j] = __builtin_amdgcn_mfma_f32_16x16x32_bf16(afl[i], bfh[j], acc[i][j], 0,0,0);
            }
    }
    #pragma unroll
    for (int i=0;i<4;i++){
        #pragma unroll
        for (int j=0;j<4;j++){
            int gc = n0 + wn + j*16 + r16;
            if (gc >= Nc) continue;
            float bv = bias ? bias[gc] : 0.f;
            #pragma unroll
            for (int r=0;r<4;r++){
                long gr = m0 + wm + i*16 + quad*4 + r;
                float v = acc[i][j][r] + bv;
                if (act) v = gelu_tanh(v);
                long o = (long)bz*sC + gr*Nc + gc;
                if (C) C[o] = v;
                if (Chi){ u16 t = f2bf(v); Chi[o] = t; if (Clo) Clo[o] = f2bf(v - bf2f(t)); }
            }
        }
    }
}

// ---------------------------------------------------------------- MFMA GEMM 64x64, grid: (M/64, N/64, batch)
__global__ __launch_bounds__(256) void gemm64_k(
    const u16* __restrict__ Ah, const u16* __restrict__ Al,
    const u16* __restrict__ Bh, const u16* __restrict__ Bl,
    float* __restrict__ C, u16* __restrict__ Chi, u16* __restrict__ Clo,
    int M, int Kc, int Nc, int lda,
    long sA, long sB, long sC, const float* __restrict__ bias, int act,
    int ktrim, int prods)
{
    __shared__ u16 sAh[64*32], sAl[64*32], sBh[64*32], sBl[64*32];
    const int m0 = blockIdx.x*64, n0 = blockIdx.y*64;
    const int bz = blockIdx.z;
    const u16* gAh = Ah + (long)bz*sA;
    const u16* gAl = Al + (long)bz*sA;
    const u16* gBh = Bh + (long)bz*sB;
    const u16* gBl = Bl + (long)bz*sB;
    const int tid = threadIdx.x;
    const int wave = tid >> 6, lane = tid & 63;
    const int quad = lane >> 4, r16 = lane & 15;
    const int wr = wave*16;
    const int kend = ktrim ? min(Kc, m0 + 64) : Kc;

    f32x4 acc[4];
    #pragma unroll
    for (int j=0;j<4;j++) acc[j] = (f32x4){0.f,0.f,0.f,0.f};

    for (int k0 = 0; k0 < kend; k0 += 32){
        __syncthreads();
        {
            int row = tid >> 2, kg = (tid & 3)*8;
            long ga = (long)(m0+row)*lda + k0 + kg;
            long gb = (long)(n0+row)*Kc + k0 + kg;
            gload16(gAh+ga, &sAh[tid*8]);
            if (prods == 3) gload16(gAl+ga, &sAl[tid*8]);
            gload16(gBh+gb, &sBh[tid*8]);
            if (prods >= 2) gload16(gBl+gb, &sBl[tid*8]);
        }
        __syncthreads();
        bf16x8 afh = *(const bf16x8*)&sAh[(wr+r16)*32 + quad*8];
        bf16x8 afl;
        if (prods == 3) afl = *(const bf16x8*)&sAl[(wr+r16)*32 + quad*8];
        #pragma unroll
        for (int j=0;j<4;j++){
            bf16x8 bh = *(const bf16x8*)&sBh[(j*16+r16)*32 + quad*8];
            acc[j] = __builtin_amdgcn_mfma_f32_16x16x32_bf16(afh, bh, acc[j], 0,0,0);
            if (prods >= 2){
                bf16x8 bl = *(const bf16x8*)&sBl[(j*16+r16)*32 + quad*8];
                acc[j] = __builtin_amdgcn_mfma_f32_16x16x32_bf16(afh, bl, acc[j], 0,0,0);
            }
            if (prods == 3)
                acc[j] = __builtin_amdgcn_mfma_f32_16x16x32_bf16(afl, bh, acc[j], 0,0,0);
        }
    }
    #pragma unroll
    for (int j=0;j<4;j++){
        int gc = n0 + j*16 + r16;
        float bv = bias ? bias[gc] : 0.f;
        #pragma unroll
        for (int r=0;r<4;r++){
            long gr = m0 + wr + quad*4 + r;
            float v = acc[j][r] + bv;
            if (act) v = gelu_tanh(v);
            long o = (long)bz*sC + gr*Nc + gc;
            if (C) C[o] = v;
            if (Chi){ u16 t = f2bf(v); Chi[o] = t; if (Clo) Clo[o] = f2bf(v - bf2f(t)); }
        }
    }
}

// ---------------------------------------------------------------- LayerNorm (rows of 512), optional split out
__global__ __launch_bounds__(256) void ln_k(
    const float* __restrict__ x, const float* __restrict__ g,
    const float* __restrict__ be, float* __restrict__ y,
    u16* __restrict__ yh, u16* __restrict__ yl)
{
    __shared__ float sh[8];
    const int r = blockIdx.x, tid = threadIdx.x;
    const float* xr = x + (long)r*KK;
    float2 v = *(const float2*)(xr + tid*2);
    float s = v.x+v.y, s2 = v.x*v.x+v.y*v.y;
    #pragma unroll
    for (int o=32;o>0;o>>=1){ s += __shfl_down(s,o); s2 += __shfl_down(s2,o); }
    if ((tid&63)==0){ sh[tid>>6]=s; sh[4+(tid>>6)]=s2; }
    __syncthreads();
    s  = sh[0]+sh[1]+sh[2]+sh[3];
    s2 = sh[4]+sh[5]+sh[6]+sh[7];
    const float mean = s*(1.f/KK);
    const float var  = s2*(1.f/KK) - mean*mean;
    const float rs = rsqrtf(var + 1e-5f);
    float2 gg = *(const float2*)(g + tid*2);
    float2 bb = *(const float2*)(be + tid*2);
    float ox = (v.x-mean)*rs*gg.x + bb.x;
    float oy = (v.y-mean)*rs*gg.y + bb.y;
    long o = (long)r*KK + tid*2;
    *(float2*)(y + o) = make_float2(ox, oy);
    if (yh){ wsplit(yh, yl, o, ox); wsplit(yh, yl, o+1, oy); }
}

// ---------------------------------------------------------------- elementwise kernels
__global__ void tfinal_k(const float* __restrict__ x, const float* __restrict__ a1,
                         const float* __restrict__ a2, const float* __restrict__ res,
                         float* __restrict__ out, u16* __restrict__ oh, u16* __restrict__ ol){
    int i = blockIdx.x*256 + threadIdx.x;
    if (i >= BN*KK/4) return;
    float4 xv = ((const float4*)x)[i];
    float4 v1 = ((const float4*)a1)[i];
    float4 v2 = ((const float4*)a2)[i];
    float4 o;
    o.x = xv.x + v1.x + 0.5f*v2.x;
    o.y = xv.y + v1.y + 0.5f*v2.y;
    o.z = xv.z + v1.z + 0.5f*v2.z;
    o.w = xv.w + v1.w + 0.5f*v2.w;
    if (res){ float4 rv = ((const float4*)res)[i]; o.x+=rv.x; o.y+=rv.y; o.z+=rv.z; o.w+=rv.w; }
    ((float4*)out)[i] = o;
    if (oh){
        long ob = (long)i*4;
        wsplit(oh, ol, ob+0, o.x); wsplit(oh, ol, ob+1, o.y);
        wsplit(oh, ol, ob+2, o.z); wsplit(oh, ol, ob+3, o.w);
    }
}
__global__ void copy_k(const float* __restrict__ s, float* __restrict__ d, int n4){
    int i = blockIdx.x*256 + threadIdx.x;
    if (i < n4) ((float4*)d)[i] = ((const float4*)s)[i];
}
__global__ void final_k(const float* __restrict__ a, const float* __restrict__ b,
                        const float* __restrict__ c, float* __restrict__ out){
    int i = blockIdx.x*256 + threadIdx.x;
    if (i >= BN*KK/4) return;
    float4 av = ((const float4*)a)[i], bv = ((const float4*)b)[i], cv = ((const float4*)c)[i];
    float4 o;
    o.x = av.x + bv.x - cv.x; o.y = av.y + bv.y - cv.y;
    o.z = av.z + bv.z - cv.z; o.w = av.w + bv.w - cv.w;
    ((float4*)out)[i] = o;
}
__global__ void ffn_update_k(const float* __restrict__ hin, float* __restrict__ hout,
                             const float* __restrict__ drive, const float* __restrict__ bmh,
                             const float* __restrict__ mup, const float* __restrict__ lr,
                             u16* __restrict__ hh){
    int i = blockIdx.x*256 + threadIdx.x;
    if (i >= BN*KK/4) return;
    const float lrv = *lr;
    float4 hv = ((const float4*)hin)[i];
    float4 dv = ((const float4*)drive)[i];
    float4 bv = ((const float4*)bmh)[i];
    float4 pv = ((const float4*)mup)[i];
    float4 o;
    o.x = hv.x + lrv*(dv.x - (1e-3f*(hv.x-pv.x) + 1.0f*(hv.x-bv.x)));
    o.y = hv.y + lrv*(dv.y - (1e-3f*(hv.y-pv.y) + 1.0f*(hv.y-bv.y)));
    o.z = hv.z + lrv*(dv.z - (1e-3f*(hv.z-pv.z) + 1.0f*(hv.z-bv.z)));
    o.w = hv.w + lrv*(dv.w - (1e-3f*(hv.w-pv.w) + 1.0f*(hv.w-bv.w)));
    ((float4*)hout)[i] = o;
    long ob = (long)i*4;
    hh[ob+0]=f2bf(o.x); hh[ob+1]=f2bf(o.y); hh[ob+2]=f2bf(o.z); hh[ob+3]=f2bf(o.w);
}

// ---------------------------------------------------------------- attention prep
__global__ __launch_bounds__(512) void prep2_k(
    const float* __restrict__ QKV, const float* __restrict__ SQSK,
    u16* __restrict__ CFh, u16* __restrict__ CFl,
    u16* __restrict__ KSh, u16* __restrict__ KSl, float* __restrict__ dvec)
{
    const int bn = blockIdx.x;
    const int b = bn / NN, n = bn % NN;
    const int h = threadIdx.x >> 6, d = threadIdx.x & 63;
    float q  = QKV[(size_t)bn*1536 + h*DHh + d];
    float k  = QKV[(size_t)bn*1536 + KK + h*DHh + d];
    float sq = SQSK[(size_t)bn*1024 + h*DHh + d] + 1e-8f;
    float sk = SQSK[(size_t)bn*1024 + KK + h*DHh + d] + 1e-8f;
    float inv = 1.f/sq;
    float nqi = -2.f*q*inv;
    float skk = sk + k*k;
    const size_t base = ((size_t)(h*BB + b)*NN + n)*128;
    wsplit(CFh, CFl, base+d,    inv);
    wsplit(CFh, CFl, base+64+d, nqi);
    wsplit(KSh, KSl, base+d,    skk);
    wsplit(KSh, KSl, base+64+d, k);
    float dv = __logf(sk);
    #pragma unroll
    for (int o=32;o>0;o>>=1) dv += __shfl_down(dv,o);
    if (d==0) dvec[((size_t)h*BB + b)*NN + n] = dv;
}

// ---------------------------------------------------------------- V transpose (hi only)
__global__ __launch_bounds__(256) void vtsplit_k(
    const float* __restrict__ QKV, u16* __restrict__ VTh)
{
    __shared__ float t[64][65];
    const int n0 = blockIdx.x * 64;
    const int h = blockIdx.y, b = blockIdx.z;
    const int tid = threadIdx.x;
    const int c4 = (tid & 15) * 4;
    const int r0 = tid >> 4;
    for (int rr = r0; rr < 64; rr += 16){
        float4 v = *(const float4*)(QKV + (size_t)(b*NN + n0 + rr)*1536 + 1024 + h*DHh + c4);
        t[c4+0][rr] = v.x; t[c4+1][rr] = v.y; t[c4+2][rr] = v.z; t[c4+3][rr] = v.w;
    }
    __syncthreads();
    for (int dd = r0; dd < 64; dd += 16){
        size_t base = ((size_t)(h*BB + b)*64 + dd)*NN + n0 + c4;
        #pragma unroll
        for (int q=0;q<4;q++) VTh[base+q] = f2bf(t[dd][c4+q]);
    }
}

// ---------------------------------------------------------------- softmax for a head-group of 4
__global__ __launch_bounds__(256) void softmax2_k(
    float* __restrict__ S, const float* __restrict__ dvec,
    float* __restrict__ betam, u16* __restrict__ BMh, int g)
{
    __shared__ float s_sc[NN];
    __shared__ float s_bm[NN];
    __shared__ float s_red[4];
    const int tid = threadIdx.x;
    const int b = blockIdx.x / NN, i = blockIdx.x % NN;
    const int L = i + 1;
    for (int j=tid;j<NN;j+=256) s_bm[j]=0.f;
    for (int hg=0; hg<4; ++hg){
        const int z = hg*BB + b;
        float* row = S + ((long)z*NN + i)*NN;
        const float* dp = dvec + ((size_t)(g*4+hg)*BB + b)*NN;
        float lm = -3.0e38f;
        for (int j=tid;j<L;j+=256){
            float sc = -0.5f*row[j] + 0.5f*dp[j];
            s_sc[j] = sc;
            lm = fmaxf(lm, sc);
        }
        #pragma unroll
        for (int o=32;o>0;o>>=1) lm = fmaxf(lm, __shfl_xor(lm, o));
        __syncthreads();
        if ((tid&63)==0) s_red[tid>>6] = lm;
        __syncthreads();
        const float mx = fmaxf(fmaxf(s_red[0],s_red[1]), fmaxf(s_red[2],s_red[3]));
        float ps = 0.f;
        for (int j=tid;j<L;j+=256){
            float e = __expf(s_sc[j]-mx);
            s_sc[j] = e;
            ps += e;
        }
        #pragma unroll
        for (int o=32;o>0;o>>=1) ps += __shfl_xor(ps, o);
        __syncthreads();
        if ((tid&63)==0) s_red[tid>>6] = ps;
        __syncthreads();
        const float isum = 1.f/(s_red[0]+s_red[1]+s_red[2]+s_red[3]);
        u16* brow = (u16*)row;
        for (int j=tid;j<NN;j+=256){
            if (j < L){
                float w = s_sc[j]*isum;
                brow[j] = f2bf(w);
                s_bm[j] += 0.125f*w;
            } else {
                brow[j] = 0;
            }
        }
        __syncthreads();
    }
    const long bmrow = ((long)b*NN + i)*NN;
    if (g == 0){
        for (int j=tid;j<NN;j+=256) betam[bmrow+j] = s_bm[j];
    } else {
        for (int j=tid;j<NN;j+=256) BMh[bmrow+j] = f2bf(betam[bmrow+j] + s_bm[j]);
    }
}

// ---------------------------------------------------------------- PV: out[i,d] = sum_j beta[i,j] V[j,d]  (bf16 x bf16-hi)
__global__ __launch_bounds__(256) void pv_k(
    const u16* __restrict__ Sbeta,
    const u16* __restrict__ VTh,
    u16* __restrict__ xh, int g)
{
    __shared__ u16 sA[64*64];
    __shared__ u16 sBh[64*64];
    const int m0 = blockIdx.x*64;
    const int z16 = blockIdx.y;
    const int b = z16 & 3, hg = z16 >> 2;
    const int head = g*4 + hg;
    const int vtz = head*BB + b;
    const int tid = threadIdx.x;
    const int wave = tid>>6, lane = tid&63;
    const int quad = lane>>4, r16 = lane&15;
    f32x4 acc[4];
    #pragma unroll
    for (int j=0;j<4;j++) acc[j]=(f32x4){0.f,0.f,0.f,0.f};
    const int jmax = m0 + 64;
    for (int j0 = 0; j0 < jmax; j0 += 64){
        __syncthreads();
        int c = tid;
        #pragma unroll
        for (int rep=0; rep<2; ++rep, c+=256){
            int row = c >> 3, k8 = (c&7)*8;
            gload16(Sbeta + ((size_t)(z16*NN + m0 + row))*(2*NN) + j0 + k8, &sA[c*8]);
            gload16(VTh + ((size_t)(vtz*64 + row))*NN + j0 + k8, &sBh[c*8]);
        }
        __syncthreads();
        #pragma unroll
        for (int kk=0; kk<2; ++kk){
            bf16x8 af = *(const bf16x8*)&sA[(wave*16 + r16)*64 + kk*32 + quad*8];
            #pragma unroll
            for (int nj=0; nj<4; ++nj){
                bf16x8 bh = *(const bf16x8*)&sBh[(nj*16 + r16)*64 + kk*32 + quad*8];
                acc[nj] = __builtin_amdgcn_mfma_f32_16x16x32_bf16(af, bh, acc[nj], 0,0,0);
            }
        }
    }
    #pragma unroll
    for (int nj=0;nj<4;nj++){
        #pragma unroll
        for (int r=0;r<4;r++){
            int i = m0 + wave*16 + quad*4 + r;
            int d = nj*16 + r16;
            size_t o = ((size_t)(b*NN)+i)*KK + head*64 + d;
            xh[o] = f2bf(acc[nj][r]);
        }
    }
}

// ---------------------------------------------------------------- launch
extern "C" void kernel_launch(void* const* d_in, const int* in_sizes, int n_in,
                              void* d_out, int out_size, void* d_ws, size_t ws_size,
                              hipStream_t stream) {
    const float* mu_q    = (const float*)d_in[0];
    const float* sigma_q = (const float*)d_in[1];
    const float* phi     = (const float*)d_in[2];
    const float* gen     = (const float*)d_in[3];
    const float* mu_prior= (const float*)d_in[5];
    const float* Wq = (const float*)d_in[6];
    const float* Wk = (const float*)d_in[7];
    const float* Wv = (const float*)d_in[8];
    const float* Wo = (const float*)d_in[9];
    const float* g1 = (const float*)d_in[10];
    const float* be1= (const float*)d_in[11];
    const float* g2 = (const float*)d_in[12];
    const float* be2= (const float*)d_in[13];
    const float* W1 = (const float*)d_in[14];
    const float* bh1= (const float*)d_in[15];
    const float* W2 = (const float*)d_in[16];
    const float* bh2= (const float*)d_in[17];
    const float* lr = (const float*)d_in[18];
    float* out = (float*)d_out;

    float* w = (float*)d_ws;
    size_t off = 0;
    auto alloc = [&](size_t n){ float* p = w + off; off += (n+3)&~(size_t)3; return p; };
    auto ualloc = [&](size_t n){ return (u16*)alloc((n+1)/2); };

    float* Xb   = alloc((size_t)BN*KK);        // mu_n -> mu_g -> mu_n2
    float* A1b  = alloc((size_t)BN*KK);
    float* A2b  = alloc((size_t)BN*KK);        // also drive
    float* QKVb = alloc((size_t)BN*3*KK);      // QKV; later WOb / Hb / MRb
    float* SQSKb= alloc((size_t)BN*2*KK);
    float* REG  = alloc((size_t)16*NN*NN);     // X3 / Sbuf / ZH
    float* Sbuf = REG;
    u16*  X3h   = (u16*)REG;
    u16*  ZH    = (u16*)REG;
    float* Db_  = alloc((size_t)HH*BB*NN);
    float* BMb  = alloc((size_t)BB*NN*NN);
    u16* AH  = ualloc((size_t)BN*HIDd); u16* AL  = ualloc((size_t)BN*HIDd);
    u16* CFh = AH;
    u16* CFl = AH + (size_t)HH*BB*NN*128;
    u16* KSh = AL;
    u16* KSl = AL + (size_t)HH*BB*NN*128;
    u16* VTh = ualloc((size_t)HH*BB*64*NN);
    u16* GFh = ualloc((size_t)3*KK*KK);
    u16* WQKVh= ualloc((size_t)3*KK*KK); u16* WQKVl= ualloc((size_t)3*KK*KK);
    u16* WSQKh= ualloc((size_t)2*KK*KK); u16* WSQKl= ualloc((size_t)2*KK*KK);
    u16* WoTh= ualloc((size_t)KK*KK);
    u16* W1Th= ualloc((size_t)KK*HIDd);
    u16* W2Th= ualloc((size_t)KK*HIDd);
    u16* BMh = ualloc((size_t)BB*NN*NN);
    u16* HTh = ualloc((size_t)BB*KK*NN);
    float* WOb = QKVb;
    float* Hb  = QKVb + (size_t)BN*KK;
    float* MRb = QKVb + 2*(size_t)BN*KK;
    float* MN2b= Xb;
    float* DRVb= A2b;

    auto gemm = [&](const u16* ah, const u16* al, const u16* bh, const u16* bl,
                    float* C, u16* chi, u16* clo, int M, int Kc, int Nc, int lda,
                    long sA, long sB, long sC, const float* bias, int act,
                    int cskip, int prods, int batch){
        dim3 g(M/128, (Nc+127)/128, batch);
        gemm_mfma_k<<<g, 256, 0, stream>>>(ah, al, bh, bl, C, chi, clo,
                                           M, Kc, Nc, lda, sA, sB, sC, bias, act, cskip, prods);
    };
    auto gemm64 = [&](const u16* ah, const u16* al, const u16* bh, const u16* bl,
                      float* C, u16* chi, u16* clo, int M, int Kc, int Nc, int lda,
                      long sA, long sB, long sC, const float* bias, int act,
                      int ktrim, int prods, int batch){
        dim3 g(M/64, Nc/64, batch);
        gemm64_k<<<g, 256, 0, stream>>>(ah, al, bh, bl, C, chi, clo,
                                        M, Kc, Nc, lda, sA, sB, sC, bias, act, ktrim, prods);
    };
    const int EW = BN*KK/4/256;   // elementwise grid

    // ---- weight prep (once) ----
    gflat_k<<<(3*KK*KK+255)/256, 256, 0, stream>>>(gen, GFh);
    {
        dim3 gq(KK/32, KK/32, 1);
        split_t_k<<<gq, 256, 0, stream>>>(Wq, WQKVh, WQKVl, KK, KK, 0L, 0L, 0);
        split_t_k<<<gq, 256, 0, stream>>>(Wk, WQKVh+(size_t)KK*KK, WQKVl+(size_t)KK*KK, KK, KK, 0L, 0L, 0);
        split_t_k<<<gq, 256, 0, stream>>>(Wv, WQKVh+2*(size_t)KK*KK, WQKVl+2*(size_t)KK*KK, KK, KK, 0L, 0L, 0);
        split_t_k<<<gq, 256, 0, stream>>>(Wo, WoTh, 0, KK, KK, 0L, 0L, 0);
        split_t_k<<<gq, 256, 0, stream>>>(Wq, WSQKh, WSQKl, KK, KK, 0L, 0L, 1);
        split_t_k<<<gq, 256, 0, stream>>>(Wk, WSQKh+(size_t)KK*KK, WSQKl+(size_t)KK*KK, KK, KK, 0L, 0L, 1);
        dim3 g1g(HIDd/32, KK/32, 1);
        split_t_k<<<g1g, 256, 0, stream>>>(W1, W1Th, 0, KK, HIDd, 0L, 0L, 0);
        dim3 g2g(KK/32, HIDd/32, 1);
        split_t_k<<<g2g, 256, 0, stream>>>(W2, W2Th, 0, HIDd, KK, 0L, 0L, 0);
    }

    // ---- phase A: LN1 + forward transport ----
    ln_k<<<BN, 256, 0, stream>>>(mu_q, g1, be1, Xb, 0, 0);
    expand3_k<<<EW, 256, 0, stream>>>(Xb, phi, X3h, 1.f);
    gemm64(X3h, X3h, GFh, GFh, A1b, 0,0, BN, 3*KK, KK, 3*KK, 0,0,0, nullptr, 0, 0, 1, 1);
    expand3_k<<<EW, 256, 0, stream>>>(A1b, phi, X3h, 1.f);
    gemm64(X3h, X3h, GFh, GFh, A2b, 0,0, BN, 3*KK, KK, 3*KK, 0,0,0, nullptr, 0, 0, 1, 1);
    tfinal_k<<<EW, 256, 0, stream>>>(Xb, A1b, A2b, nullptr, Xb, AH, AL);   // mu_g + split

    // ---- phase B: fused projections + attention prep ----
    gemm(AH, AL, WQKVh, WQKVl, QKVb, 0,0, BN, KK, 3*KK, KK, 0,0,0, nullptr, 0, 0, 3, 1);
    split_k<<<(int)(((long)BN*KK+255)/256), 256, 0, stream>>>(sigma_q, AH, AL, (long)BN*KK);
    gemm(AH, AL, WSQKh, WSQKl, SQSKb, 0,0, BN, KK, 2*KK, KK, 0,0,0, nullptr, 0, 0, 3, 1);
    prep2_k<<<BN, 512, 0, stream>>>(QKVb, SQSKb, CFh, CFl, KSh, KSl, Db_);
    {
        dim3 tg(NN/64, HH, BB);
        vtsplit_k<<<tg, 256, 0, stream>>>(QKVb, VTh);
    }

    // ---- phase C: attention, two head-groups of 4 ----
    for (int g = 0; g < 2; ++g){
        size_t cfo = (size_t)g*4*BB*NN*128;
        gemm(CFh+cfo, CFl+cfo, KSh+cfo, KSl+cfo, Sbuf, 0,0,
             NN, 128, NN, 128, (long)NN*128, (long)NN*128, (long)NN*NN,
             nullptr, 0, 1, 3, 16);
        softmax2_k<<<BB*NN, 256, 0, stream>>>(Sbuf, Db_, BMb, BMh, g);
        dim3 pg(NN/64, 16, 1);
        pv_k<<<pg, 256, 0, stream>>>((const u16*)Sbuf, VTh, AH, g);
    }

    // ---- phase D: output proj + back transport + residual + LN2 ----
    gemm64(AH, AH, WoTh, WoTh, WOb, 0,0, BN, KK, KK, KK, 0,0,0, nullptr, 0, 0, 1, 1);
    expand3_k<<<EW, 256, 0, stream>>>(WOb, phi, X3h, -1.f);
    gemm64(X3h, X3h, GFh, GFh, A1b, 0,0, BN, 3*KK, KK, 3*KK, 0,0,0, nullptr, 0, 0, 1, 1);
    expand3_k<<<EW, 256, 0, stream>>>(A1b, phi, X3h, -1.f);
    gemm64(X3h, X3h, GFh, GFh, A2b, 0,0, BN, 3*KK, KK, 3*KK, 0,0,0, nullptr, 0, 0, 1, 1);
    tfinal_k<<<EW, 256, 0, stream>>>(WOb, A1b, A2b, mu_q, MRb, 0,0);        // mu_res
    ln_k<<<BN, 256, 0, stream>>>(MRb, g2, be2, MN2b, AH, 0);                // mu_n2 + hi split

    // ---- phase E: 2 VFE iterations ----
    for (int it=0; it<2; ++it){
        const float* hin = (it==0) ? MN2b : Hb;
        gemm(AH, AH, W1Th, W1Th, 0, ZH, 0, BN, KK, HIDd, KK, 0,0,0, bh1, 1, 0, 1, 1);
        gemm64(ZH, ZH, W2Th, W2Th, DRVb, 0,0, BN, HIDd, KK, HIDd, 0,0,0, bh2, 0, 0, 1, 1);
        {
            dim3 tg(KK/32, NN/32, BB);
            split_t_k<<<tg, 256, 0, stream>>>(hin, HTh, 0, NN, KK,
                                              (long)NN*KK, (long)KK*NN, 0);
        }
        {
            dim3 bg(NN/64, KK/64, BB);
            gemm64_k<<<bg, 256, 0, stream>>>(BMh, BMh, HTh, HTh, A1b, 0,0,
                                             NN, NN, KK, NN,
                                             (long)NN*NN, (long)KK*NN, (long)NN*KK,
                                             nullptr, 0, 1, 1);
        }
        ffn_update_k<<<EW, 256, 0, stream>>>(hin, Hb, DRVb, A1b, mu_prior, lr, AH);
    }

    // ---- phase F: outputs ----
    final_k<<<EW, 256, 0, stream>>>(MRb, Hb, MN2b, out);
    copy_k<<<EW, 256, 0, stream>>>(sigma_q, out + (size_t)BN*KK, BN*KK/4);
    copy_k<<<(BN*3/4+255)/256, 256, 0, stream>>>(phi, out + 2*(size_t)BN*KK, BN*3/4);

    (void)in_sizes; (void)n_in; (void)out_size; (void)ws_size;
}

// Round 9
// 743.032 us; speedup vs baseline: 1.4529x; 1.0431x over previous
//
#include <hip/hip_runtime.h>
#include <math.h>

#define BB 4
#define NN 1024
#define KK 512
#define HH 8
#define DHh 64
#define HIDd 2048
#define BN (BB*NN)

typedef unsigned short u16;
typedef __attribute__((ext_vector_type(8))) short bf16x8;
typedef __attribute__((ext_vector_type(4))) float f32x4;

// ---------------------------------------------------------------- helpers
__device__ __forceinline__ float gelu_tanh(float x){
    float x3 = x*x*x;
    float t = tanhf(0.7978845608028654f*(x + 0.044715f*x3));
    return 0.5f*x*(1.0f+t);
}
__device__ __forceinline__ u16 f2bf(float x){
    unsigned int u = __float_as_uint(x);
    unsigned int r = (u + 0x7fffu + ((u>>16)&1u)) >> 16;
    return (u16)r;
}
__device__ __forceinline__ float bf2f(u16 b){
    return __uint_as_float(((unsigned int)b)<<16);
}
__device__ __forceinline__ void gload16(const void* g, void* l){
    __builtin_amdgcn_global_load_lds((__attribute__((address_space(1))) void*)g,
                                     (__attribute__((address_space(3))) void*)l, 16, 0, 0);
}
__device__ __forceinline__ void wsplit(u16* hi, u16* lo, size_t o, float v){
    u16 h = f2bf(v);
    hi[o] = h;
    if (lo) lo[o] = f2bf(v - bf2f(h));
}

// ---------------------------------------------------------------- split conversions
__global__ __launch_bounds__(256) void split_k(const float* __restrict__ src,
                                               u16* __restrict__ hi, u16* __restrict__ lo, long n){
    long i = (long)blockIdx.x*256 + threadIdx.x;
    if (i >= n) return;
    wsplit(hi, lo, i, src[i]);
}

// generic transpose-split  src [Kc][Nc] -> dst [Nc][Kc]
__global__ __launch_bounds__(256) void split_t_k(
    const float* __restrict__ src, u16* __restrict__ hi, u16* __restrict__ lo,
    int Kc, int Nc, long sS, long sD, int square)
{
    __shared__ float t[32][33];
    const int n0 = blockIdx.x*32, k0 = blockIdx.y*32, bz = blockIdx.z;
    const float* S = src + (long)bz*sS;
    const int tx = threadIdx.x & 31, ty = threadIdx.x >> 5;
    for (int r = ty; r < 32; r += 8){
        float v = S[(long)(k0+r)*Nc + n0+tx];
        if (square) v *= v;
        t[r][tx] = v;
    }
    __syncthreads();
    for (int r = ty; r < 32; r += 8){
        float v = t[tx][r];
        long o = (long)bz*sD + (long)(n0+r)*Kc + k0 + tx;
        wsplit(hi, lo, o, v);
    }
}

// batched weight prep: 6 KK x KK transposes in one dispatch (z selects src/dst/square)
__global__ __launch_bounds__(256) void wprep_k(
    const float* __restrict__ Wq, const float* __restrict__ Wk,
    const float* __restrict__ Wv, const float* __restrict__ Wo,
    u16* __restrict__ WQKVh, u16* __restrict__ WQKVl,
    u16* __restrict__ WoTh, u16* __restrict__ WSQKh, u16* __restrict__ WSQKl)
{
    __shared__ float t[32][33];
    const int z = blockIdx.z;
    const float* src; u16* hi; u16* lo; int sq;
    const size_t KK2 = (size_t)KK*KK;
    if      (z==0){ src=Wq; hi=WQKVh;        lo=WQKVl;        sq=0; }
    else if (z==1){ src=Wk; hi=WQKVh+KK2;    lo=WQKVl+KK2;    sq=0; }
    else if (z==2){ src=Wv; hi=WQKVh+2*KK2;  lo=WQKVl+2*KK2;  sq=0; }
    else if (z==3){ src=Wo; hi=WoTh;         lo=0;            sq=0; }
    else if (z==4){ src=Wq; hi=WSQKh;        lo=WSQKl;        sq=1; }
    else          { src=Wk; hi=WSQKh+KK2;    lo=WSQKl+KK2;    sq=1; }
    const int n0 = blockIdx.x*32, k0 = blockIdx.y*32;
    const int tx = threadIdx.x & 31, ty = threadIdx.x >> 5;
    for (int r = ty; r < 32; r += 8){
        float v = src[(long)(k0+r)*KK + n0+tx];
        if (sq) v *= v;
        t[r][tx] = v;
    }
    __syncthreads();
    for (int r = ty; r < 32; r += 8){
        float v = t[tx][r];
        long o = (long)(n0+r)*KK + k0 + tx;
        wsplit(hi, lo, o, v);
    }
}

// gen (3,K,K) -> Gflat[k][g*512+l] bf16 hi only
__global__ __launch_bounds__(256) void gflat_k(const float* __restrict__ gen,
                                               u16* __restrict__ hi){
    int idx = blockIdx.x*256 + threadIdx.x;
    if (idx >= 3*KK*KK) return;
    int g = idx / (KK*KK);
    int rem = idx % (KK*KK);
    int k = rem / KK, l = rem % KK;
    hi[(size_t)k*(3*KK) + g*KK + l] = f2bf(gen[idx]);
}

// ---------------------------------------------------------------- MFMA GEMM 128x128, grid: (M/128, N/128, batch)
__global__ __launch_bounds__(256) void gemm_mfma_k(
    const u16* __restrict__ Ah, const u16* __restrict__ Al,
    const u16* __restrict__ Bh, const u16* __restrict__ Bl,
    float* __restrict__ C, u16* __restrict__ Chi, u16* __restrict__ Clo,
    int M, int Kc, int Nc, int lda,
    long sA, long sB, long sC, const float* __restrict__ bias, int act,
    int cskip, int prods)
{
    __shared__ u16 sAh[128*32], sAl[128*32], sBh[128*32], sBl[128*32];
    const int m0 = blockIdx.x*128, n0 = blockIdx.y*128;
    if (cskip == 1 && n0 > m0 + 127) return;
    const int bz = blockIdx.z;
    const u16* gAh = Ah + (long)bz*sA;
    const u16* gAl = Al + (long)bz*sA;
    const u16* gBh = Bh + (long)bz*sB;
    const u16* gBl = Bl + (long)bz*sB;
    const int tid = threadIdx.x;
    const int wave = tid >> 6, lane = tid & 63;
    const int quad = lane >> 4, r16 = lane & 15;
    const int wm = (wave>>1)*64, wn = (wave&1)*64;

    f32x4 acc[4][4];
    #pragma unroll
    for (int i=0;i<4;i++)
        #pragma unroll
        for (int j=0;j<4;j++) acc[i][j] = (f32x4){0.f,0.f,0.f,0.f};

    for (int k0 = 0; k0 < Kc; k0 += 32){
        __syncthreads();
        #pragma unroll
        for (int half=0; half<2; ++half){
            int c = half*256 + tid;
            int row = c >> 2, kg = (c & 3)*8;
            long ga = (long)(m0+row)*lda + k0 + kg;
            long gb = (long)(n0+row)*Kc + k0 + kg;
            gload16(gAh+ga, &sAh[c*8]);
            if (prods == 3) gload16(gAl+ga, &sAl[c*8]);
            gload16(gBh+gb, &sBh[c*8]);
            if (prods >= 2) gload16(gBl+gb, &sBl[c*8]);
        }
        __syncthreads();
        bf16x8 afh[4], afl[4], bfh[4], bfl[4];
        #pragma unroll
        for (int i=0;i<4;i++){
            afh[i] = *(const bf16x8*)&sAh[(wm+i*16+r16)*32 + quad*8];
            bfh[i] = *(const bf16x8*)&sBh[(wn+i*16+r16)*32 + quad*8];
        }
        if (prods >= 2)
            #pragma unroll
            for (int i=0;i<4;i++) bfl[i] = *(const bf16x8*)&sBl[(wn+i*16+r16)*32 + quad*8];
        if (prods == 3)
            #pragma unroll
            for (int i=0;i<4;i++) afl[i] = *(const bf16x8*)&sAl[(wm+i*16+r16)*32 + quad*8];
        #pragma unroll
        for (int i=0;i<4;i++)
            #pragma unroll
            for (int j=0;j<4;j++){
                acc[i][j] = __builtin_amdgcn_mfma_f32_16x16x32_bf16(afh[i], bfh[j], acc[i][j], 0,0,0);
                if (prods >= 2)
                    acc[i][j] = __builtin_amdgcn_mfma_f32_16x16x32_bf16(afh[i], bfl[j], acc[i][j], 0,0,0);
                if (prods == 3)
                    acc[i][j] = __builtin_amdgcn_mfma_f32_16x16x32_bf16(afl[i], bfh[j], acc[i][j], 0,0,0);
            }
    }
    #pragma unroll
    for (int i=0;i<4;i++){
        #pragma unroll
        for (int j=0;j<4;j++){
            int gc = n0 + wn + j*16 + r16;
            if (gc >= Nc) continue;
            float bv = bias ? bias[gc] : 0.f;
            #pragma unroll
            for (int r=0;r<4;r++){
                long gr = m0 + wm + i*16 + quad*4 + r;
                float v = acc[i][j][r] + bv;
                if (act) v = gelu_tanh(v);
                long o = (long)bz*sC + gr*Nc + gc;
                if (C) C[o] = v;
                if (Chi){ u16 t = f2bf(v); Chi[o] = t; if (Clo) Clo[o] = f2bf(v - bf2f(t)); }
            }
        }
    }
}

// ---------------------------------------------------------------- MFMA GEMM 64x64, grid: (M/64, N/64, batch)
// optional epilogue phi-expand: X3e[gr*1536 + g*512 + gc] = esign*phi[gr,g]*v
__global__ __launch_bounds__(256) void gemm64_k(
    const u16* __restrict__ Ah, const u16* __restrict__ Al,
    const u16* __restrict__ Bh, const u16* __restrict__ Bl,
    float* __restrict__ C, u16* __restrict__ Chi, u16* __restrict__ Clo,
    int M, int Kc, int Nc, int lda,
    long sA, long sB, long sC, const float* __restrict__ bias, int act,
    int ktrim, int prods,
    const float* __restrict__ phi, u16* __restrict__ X3e, float esign)
{
    __shared__ u16 sAh[64*32], sAl[64*32], sBh[64*32], sBl[64*32];
    const int m0 = blockIdx.x*64, n0 = blockIdx.y*64;
    const int bz = blockIdx.z;
    const u16* gAh = Ah + (long)bz*sA;
    const u16* gAl = Al + (long)bz*sA;
    const u16* gBh = Bh + (long)bz*sB;
    const u16* gBl = Bl + (long)bz*sB;
    const int tid = threadIdx.x;
    const int wave = tid >> 6, lane = tid & 63;
    const int quad = lane >> 4, r16 = lane & 15;
    const int wr = wave*16;
    const int kend = ktrim ? min(Kc, m0 + 64) : Kc;

    f32x4 acc[4];
    #pragma unroll
    for (int j=0;j<4;j++) acc[j] = (f32x4){0.f,0.f,0.f,0.f};

    for (int k0 = 0; k0 < kend; k0 += 32){
        __syncthreads();
        {
            int row = tid >> 2, kg = (tid & 3)*8;
            long ga = (long)(m0+row)*lda + k0 + kg;
            long gb = (long)(n0+row)*Kc + k0 + kg;
            gload16(gAh+ga, &sAh[tid*8]);
            if (prods == 3) gload16(gAl+ga, &sAl[tid*8]);
            gload16(gBh+gb, &sBh[tid*8]);
            if (prods >= 2) gload16(gBl+gb, &sBl[tid*8]);
        }
        __syncthreads();
        bf16x8 afh = *(const bf16x8*)&sAh[(wr+r16)*32 + quad*8];
        bf16x8 afl;
        if (prods == 3) afl = *(const bf16x8*)&sAl[(wr+r16)*32 + quad*8];
        #pragma unroll
        for (int j=0;j<4;j++){
            bf16x8 bh = *(const bf16x8*)&sBh[(j*16+r16)*32 + quad*8];
            acc[j] = __builtin_amdgcn_mfma_f32_16x16x32_bf16(afh, bh, acc[j], 0,0,0);
            if (prods >= 2){
                bf16x8 bl = *(const bf16x8*)&sBl[(j*16+r16)*32 + quad*8];
                acc[j] = __builtin_amdgcn_mfma_f32_16x16x32_bf16(afh, bl, acc[j], 0,0,0);
            }
            if (prods == 3)
                acc[j] = __builtin_amdgcn_mfma_f32_16x16x32_bf16(afl, bh, acc[j], 0,0,0);
        }
    }
    #pragma unroll
    for (int j=0;j<4;j++){
        int gc = n0 + j*16 + r16;
        float bv = bias ? bias[gc] : 0.f;
        #pragma unroll
        for (int r=0;r<4;r++){
            long gr = m0 + wr + quad*4 + r;
            float v = acc[j][r] + bv;
            if (act) v = gelu_tanh(v);
            long o = (long)bz*sC + gr*Nc + gc;
            if (C) C[o] = v;
            if (Chi){ u16 t = f2bf(v); Chi[o] = t; if (Clo) Clo[o] = f2bf(v - bf2f(t)); }
            if (X3e){
                const float* ph = phi + gr*3;
                size_t b = (size_t)gr*(3*KK) + gc;
                X3e[b]        = f2bf(esign*ph[0]*v);
                X3e[b+KK]     = f2bf(esign*ph[1]*v);
                X3e[b+2*KK]   = f2bf(esign*ph[2]*v);
            }
        }
    }
}

// ---------------------------------------------------------------- LayerNorm (rows of 512), optional split / phi-expand out
__global__ __launch_bounds__(256) void ln_k(
    const float* __restrict__ x, const float* __restrict__ g,
    const float* __restrict__ be, float* __restrict__ y,
    u16* __restrict__ yh, u16* __restrict__ yl,
    const float* __restrict__ phi, u16* __restrict__ x3, float esign)
{
    __shared__ float sh[8];
    const int r = blockIdx.x, tid = threadIdx.x;
    const float* xr = x + (long)r*KK;
    float2 v = *(const float2*)(xr + tid*2);
    float s = v.x+v.y, s2 = v.x*v.x+v.y*v.y;
    #pragma unroll
    for (int o=32;o>0;o>>=1){ s += __shfl_down(s,o); s2 += __shfl_down(s2,o); }
    if ((tid&63)==0){ sh[tid>>6]=s; sh[4+(tid>>6)]=s2; }
    __syncthreads();
    s  = sh[0]+sh[1]+sh[2]+sh[3];
    s2 = sh[4]+sh[5]+sh[6]+sh[7];
    const float mean = s*(1.f/KK);
    const float var  = s2*(1.f/KK) - mean*mean;
    const float rs = rsqrtf(var + 1e-5f);
    float2 gg = *(const float2*)(g + tid*2);
    float2 bb = *(const float2*)(be + tid*2);
    float ox = (v.x-mean)*rs*gg.x + bb.x;
    float oy = (v.y-mean)*rs*gg.y + bb.y;
    long o = (long)r*KK + tid*2;
    *(float2*)(y + o) = make_float2(ox, oy);
    if (yh){ wsplit(yh, yl, o, ox); wsplit(yh, yl, o+1, oy); }
    if (x3){
        const float* ph = phi + r*3;
        size_t b = (size_t)r*(3*KK) + tid*2;
        #pragma unroll
        for (int gg2=0; gg2<3; ++gg2){
            float p = esign*ph[gg2];
            x3[b + gg2*KK]     = f2bf(p*ox);
            x3[b + gg2*KK + 1] = f2bf(p*oy);
        }
    }
}

// ---------------------------------------------------------------- fused residual + LayerNorm (phase D)
// mr = wo + a1 + 0.5*a2 + res  -> MRb ;  LN(mr) -> MN2b fp32 + AH bf16-hi
__global__ __launch_bounds__(256) void resln_k(
    const float* __restrict__ wo, const float* __restrict__ a1,
    const float* __restrict__ a2, const float* __restrict__ res,
    const float* __restrict__ g, const float* __restrict__ be,
    float* __restrict__ mrb, float* __restrict__ mn2, u16* __restrict__ yh)
{
    __shared__ float sh[8];
    const int r = blockIdx.x, tid = threadIdx.x;
    long o = (long)r*KK + tid*2;
    float2 xv = *(const float2*)(wo + o);
    float2 v1 = *(const float2*)(a1 + o);
    float2 v2 = *(const float2*)(a2 + o);
    float2 rv = *(const float2*)(res + o);
    float mx = xv.x + v1.x + 0.5f*v2.x + rv.x;
    float my = xv.y + v1.y + 0.5f*v2.y + rv.y;
    *(float2*)(mrb + o) = make_float2(mx, my);
    float s = mx+my, s2 = mx*mx+my*my;
    #pragma unroll
    for (int of=32;of>0;of>>=1){ s += __shfl_down(s,of); s2 += __shfl_down(s2,of); }
    if ((tid&63)==0){ sh[tid>>6]=s; sh[4+(tid>>6)]=s2; }
    __syncthreads();
    s  = sh[0]+sh[1]+sh[2]+sh[3];
    s2 = sh[4]+sh[5]+sh[6]+sh[7];
    const float mean = s*(1.f/KK);
    const float var  = s2*(1.f/KK) - mean*mean;
    const float rs = rsqrtf(var + 1e-5f);
    float2 gg = *(const float2*)(g + tid*2);
    float2 bb = *(const float2*)(be + tid*2);
    float ox = (mx-mean)*rs*gg.x + bb.x;
    float oy = (my-mean)*rs*gg.y + bb.y;
    *(float2*)(mn2 + o) = make_float2(ox, oy);
    yh[o] = f2bf(ox); yh[o+1] = f2bf(oy);
}

// ---------------------------------------------------------------- elementwise kernels
__global__ void tfinal_k(const float* __restrict__ x, const float* __restrict__ a1,
                         const float* __restrict__ a2, const float* __restrict__ res,
                         float* __restrict__ out, u16* __restrict__ oh, u16* __restrict__ ol){
    int i = blockIdx.x*256 + threadIdx.x;
    if (i >= BN*KK/4) return;
    float4 xv = ((const float4*)x)[i];
    float4 v1 = ((const float4*)a1)[i];
    float4 v2 = ((const float4*)a2)[i];
    float4 o;
    o.x = xv.x + v1.x + 0.5f*v2.x;
    o.y = xv.y + v1.y + 0.5f*v2.y;
    o.z = xv.z + v1.z + 0.5f*v2.z;
    o.w = xv.w + v1.w + 0.5f*v2.w;
    if (res){ float4 rv = ((const float4*)res)[i]; o.x+=rv.x; o.y+=rv.y; o.z+=rv.z; o.w+=rv.w; }
    ((float4*)out)[i] = o;
    if (oh){
        long ob = (long)i*4;
        wsplit(oh, ol, ob+0, o.x); wsplit(oh, ol, ob+1, o.y);
        wsplit(oh, ol, ob+2, o.z); wsplit(oh, ol, ob+3, o.w);
    }
}
__global__ void copy_k(const float* __restrict__ s, float* __restrict__ d, int n4){
    int i = blockIdx.x*256 + threadIdx.x;
    if (i < n4) ((float4*)d)[i] = ((const float4*)s)[i];
}
// h_out = h_in + lr*(drive - grad); fin: out = mrb + h_out - mn2 (skip hout/hh)
__global__ void ffn_update_k(const float* __restrict__ hin, float* __restrict__ hout,
                             const float* __restrict__ drive, const float* __restrict__ bmh,
                             const float* __restrict__ mup, const float* __restrict__ lr,
                             u16* __restrict__ hh,
                             const float* __restrict__ mrb, const float* __restrict__ mn2,
                             float* __restrict__ outp, int fin){
    int i = blockIdx.x*256 + threadIdx.x;
    if (i >= BN*KK/4) return;
    const float lrv = *lr;
    float4 hv = ((const float4*)hin)[i];
    float4 dv = ((const float4*)drive)[i];
    float4 bv = ((const float4*)bmh)[i];
    float4 pv = ((const float4*)mup)[i];
    float4 o;
    o.x = hv.x + lrv*(dv.x - (1e-3f*(hv.x-pv.x) + 1.0f*(hv.x-bv.x)));
    o.y = hv.y + lrv*(dv.y - (1e-3f*(hv.y-pv.y) + 1.0f*(hv.y-bv.y)));
    o.z = hv.z + lrv*(dv.z - (1e-3f*(hv.z-pv.z) + 1.0f*(hv.z-bv.z)));
    o.w = hv.w + lrv*(dv.w - (1e-3f*(hv.w-pv.w) + 1.0f*(hv.w-bv.w)));
    if (fin){
        float4 mr = ((const float4*)mrb)[i];
        float4 mn = ((const float4*)mn2)[i];
        float4 f;
        f.x = mr.x + o.x - mn.x; f.y = mr.y + o.y - mn.y;
        f.z = mr.z + o.z - mn.z; f.w = mr.w + o.w - mn.w;
        ((float4*)outp)[i] = f;
    } else {
        ((float4*)hout)[i] = o;
        long ob = (long)i*4;
        hh[ob+0]=f2bf(o.x); hh[ob+1]=f2bf(o.y); hh[ob+2]=f2bf(o.z); hh[ob+3]=f2bf(o.w);
    }
}

// ---------------------------------------------------------------- attention prep
__global__ __launch_bounds__(512) void prep2_k(
    const float* __restrict__ QKV, const float* __restrict__ SQSK,
    u16* __restrict__ CFh, u16* __restrict__ CFl,
    u16* __restrict__ KSh, u16* __restrict__ KSl, float* __restrict__ dvec)
{
    const int bn = blockIdx.x;
    const int b = bn / NN, n = bn % NN;
    const int h = threadIdx.x >> 6, d = threadIdx.x & 63;
    float q  = QKV[(size_t)bn*1536 + h*DHh + d];
    float k  = QKV[(size_t)bn*1536 + KK + h*DHh + d];
    float sq = SQSK[(size_t)bn*1024 + h*DHh + d] + 1e-8f;
    float sk = SQSK[(size_t)bn*1024 + KK + h*DHh + d] + 1e-8f;
    float inv = 1.f/sq;
    float nqi = -2.f*q*inv;
    float skk = sk + k*k;
    const size_t base = ((size_t)(h*BB + b)*NN + n)*128;
    wsplit(CFh, CFl, base+d,    inv);
    wsplit(CFh, CFl, base+64+d, nqi);
    wsplit(KSh, KSl, base+d,    skk);
    wsplit(KSh, KSl, base+64+d, k);
    float dv = __logf(sk);
    #pragma unroll
    for (int o=32;o>0;o>>=1) dv += __shfl_down(dv,o);
    if (d==0) dvec[((size_t)h*BB + b)*NN + n] = dv;
}

// ---------------------------------------------------------------- V transpose (hi only)
__global__ __launch_bounds__(256) void vtsplit_k(
    const float* __restrict__ QKV, u16* __restrict__ VTh)
{
    __shared__ float t[64][65];
    const int n0 = blockIdx.x * 64;
    const int h = blockIdx.y, b = blockIdx.z;
    const int tid = threadIdx.x;
    const int c4 = (tid & 15) * 4;
    const int r0 = tid >> 4;
    for (int rr = r0; rr < 64; rr += 16){
        float4 v = *(const float4*)(QKV + (size_t)(b*NN + n0 + rr)*1536 + 1024 + h*DHh + c4);
        t[c4+0][rr] = v.x; t[c4+1][rr] = v.y; t[c4+2][rr] = v.z; t[c4+3][rr] = v.w;
    }
    __syncthreads();
    for (int dd = r0; dd < 64; dd += 16){
        size_t base = ((size_t)(h*BB + b)*64 + dd)*NN + n0 + c4;
        #pragma unroll
        for (int q=0;q<4;q++) VTh[base+q] = f2bf(t[dd][c4+q]);
    }
}

// ---------------------------------------------------------------- softmax for a head-group of 4
__global__ __launch_bounds__(256) void softmax2_k(
    float* __restrict__ S, const float* __restrict__ dvec,
    float* __restrict__ betam, u16* __restrict__ BMh, int g)
{
    __shared__ float s_sc[NN];
    __shared__ float s_bm[NN];
    __shared__ float s_red[4];
    const int tid = threadIdx.x;
    const int b = blockIdx.x / NN, i = blockIdx.x % NN;
    const int L = i + 1;
    for (int j=tid;j<NN;j+=256) s_bm[j]=0.f;
    for (int hg=0; hg<4; ++hg){
        const int z = hg*BB + b;
        float* row = S + ((long)z*NN + i)*NN;
        const float* dp = dvec + ((size_t)(g*4+hg)*BB + b)*NN;
        float lm = -3.0e38f;
        for (int j=tid;j<L;j+=256){
            float sc = -0.5f*row[j] + 0.5f*dp[j];
            s_sc[j] = sc;
            lm = fmaxf(lm, sc);
        }
        #pragma unroll
        for (int o=32;o>0;o>>=1) lm = fmaxf(lm, __shfl_xor(lm, o));
        __syncthreads();
        if ((tid&63)==0) s_red[tid>>6] = lm;
        __syncthreads();
        const float mx = fmaxf(fmaxf(s_red[0],s_red[1]), fmaxf(s_red[2],s_red[3]));
        float ps = 0.f;
        for (int j=tid;j<L;j+=256){
            float e = __expf(s_sc[j]-mx);
            s_sc[j] = e;
            ps += e;
        }
        #pragma unroll
        for (int o=32;o>0;o>>=1) ps += __shfl_xor(ps, o);
        __syncthreads();
        if ((tid&63)==0) s_red[tid>>6] = ps;
        __syncthreads();
        const float isum = 1.f/(s_red[0]+s_red[1]+s_red[2]+s_red[3]);
        u16* brow = (u16*)row;
        for (int j=tid;j<NN;j+=256){
            if (j < L){
                float w = s_sc[j]*isum;
                brow[j] = f2bf(w);
                s_bm[j] += 0.125f*w;
            } else {
                brow[j] = 0;
            }
        }
        __syncthreads();
    }
    const long bmrow = ((long)b*NN + i)*NN;
    if (g == 0){
        for (int j=tid;j<NN;j+=256) betam[bmrow+j] = s_bm[j];
    } else {
        for (int j=tid;j<NN;j+=256) BMh[bmrow+j] = f2bf(betam[bmrow+j] + s_bm[j]);
    }
}

// ---------------------------------------------------------------- PV
__global__ __launch_bounds__(256) void pv_k(
    const u16* __restrict__ Sbeta,
    const u16* __restrict__ VTh,
    u16* __restrict__ xh, int g)
{
    __shared__ u16 sA[64*64];
    __shared__ u16 sBh[64*64];
    const int m0 = blockIdx.x*64;
    const int z16 = blockIdx.y;
    const int b = z16 & 3, hg = z16 >> 2;
    const int head = g*4 + hg;
    const int vtz = head*BB + b;
    const int tid = threadIdx.x;
    const int wave = tid>>6, lane = tid&63;
    const int quad = lane>>4, r16 = lane&15;
    f32x4 acc[4];
    #pragma unroll
    for (int j=0;j<4;j++) acc[j]=(f32x4){0.f,0.f,0.f,0.f};
    const int jmax = m0 + 64;
    for (int j0 = 0; j0 < jmax; j0 += 64){
        __syncthreads();
        int c = tid;
        #pragma unroll
        for (int rep=0; rep<2; ++rep, c+=256){
            int row = c >> 3, k8 = (c&7)*8;
            gload16(Sbeta + ((size_t)(z16*NN + m0 + row))*(2*NN) + j0 + k8, &sA[c*8]);
            gload16(VTh + ((size_t)(vtz*64 + row))*NN + j0 + k8, &sBh[c*8]);
        }
        __syncthreads();
        #pragma unroll
        for (int kk=0; kk<2; ++kk){
            bf16x8 af = *(const bf16x8*)&sA[(wave*16 + r16)*64 + kk*32 + quad*8];
            #pragma unroll
            for (int nj=0; nj<4; ++nj){
                bf16x8 bh = *(const bf16x8*)&sBh[(nj*16 + r16)*64 + kk*32 + quad*8];
                acc[nj] = __builtin_amdgcn_mfma_f32_16x16x32_bf16(af, bh, acc[nj], 0,0,0);
            }
        }
    }
    #pragma unroll
    for (int nj=0;nj<4;nj++){
        #pragma unroll
        for (int r=0;r<4;r++){
            int i = m0 + wave*16 + quad*4 + r;
            int d = nj*16 + r16;
            size_t o = ((size_t)(b*NN)+i)*KK + head*64 + d;
            xh[o] = f2bf(acc[nj][r]);
        }
    }
}

// ---------------------------------------------------------------- launch
extern "C" void kernel_launch(void* const* d_in, const int* in_sizes, int n_in,
                              void* d_out, int out_size, void* d_ws, size_t ws_size,
                              hipStream_t stream) {
    const float* mu_q    = (const float*)d_in[0];
    const float* sigma_q = (const float*)d_in[1];
    const float* phi     = (const float*)d_in[2];
    const float* gen     = (const float*)d_in[3];
    const float* mu_prior= (const float*)d_in[5];
    const float* Wq = (const float*)d_in[6];
    const float* Wk = (const float*)d_in[7];
    const float* Wv = (const float*)d_in[8];
    const float* Wo = (const float*)d_in[9];
    const float* g1 = (const float*)d_in[10];
    const float* be1= (const float*)d_in[11];
    const float* g2 = (const float*)d_in[12];
    const float* be2= (const float*)d_in[13];
    const float* W1 = (const float*)d_in[14];
    const float* bh1= (const float*)d_in[15];
    const float* W2 = (const float*)d_in[16];
    const float* bh2= (const float*)d_in[17];
    const float* lr = (const float*)d_in[18];
    float* out = (float*)d_out;

    float* w = (float*)d_ws;
    size_t off = 0;
    auto alloc = [&](size_t n){ float* p = w + off; off += (n+3)&~(size_t)3; return p; };
    auto ualloc = [&](size_t n){ return (u16*)alloc((n+1)/2); };

    float* Xb   = alloc((size_t)BN*KK);        // mu_n -> mu_g -> mu_n2
    float* A1b  = alloc((size_t)BN*KK);
    float* A2b  = alloc((size_t)BN*KK);        // also drive
    float* QKVb = alloc((size_t)BN*3*KK);      // QKV; later WOb / Hb / MRb
    float* SQSKb= alloc((size_t)BN*2*KK);
    float* REG  = alloc((size_t)16*NN*NN);     // X3a/X3b / Sbuf / ZH
    float* Sbuf = REG;
    u16*  X3a   = (u16*)REG;
    u16*  X3b   = X3a + (size_t)BN*3*KK;
    u16*  ZH    = (u16*)REG;
    float* Db_  = alloc((size_t)HH*BB*NN);
    float* BMb  = alloc((size_t)BB*NN*NN);
    u16* AH  = ualloc((size_t)BN*HIDd); u16* AL  = ualloc((size_t)BN*HIDd);
    u16* CFh = AH;
    u16* CFl = AH + (size_t)HH*BB*NN*128;
    u16* KSh = AL;
    u16* KSl = AL + (size_t)HH*BB*NN*128;
    u16* VTh = ualloc((size_t)HH*BB*64*NN);
    u16* GFh = ualloc((size_t)3*KK*KK);
    u16* WQKVh= ualloc((size_t)3*KK*KK); u16* WQKVl= ualloc((size_t)3*KK*KK);
    u16* WSQKh= ualloc((size_t)2*KK*KK); u16* WSQKl= ualloc((size_t)2*KK*KK);
    u16* WoTh= ualloc((size_t)KK*KK);
    u16* W1Th= ualloc((size_t)KK*HIDd);
    u16* W2Th= ualloc((size_t)KK*HIDd);
    u16* BMh = ualloc((size_t)BB*NN*NN);
    u16* HTh = ualloc((size_t)BB*KK*NN);
    float* WOb = QKVb;
    float* Hb  = QKVb + (size_t)BN*KK;
    float* MRb = QKVb + 2*(size_t)BN*KK;
    float* MN2b= Xb;
    float* DRVb= A2b;

    auto gemm = [&](const u16* ah, const u16* al, const u16* bh, const u16* bl,
                    float* C, u16* chi, u16* clo, int M, int Kc, int Nc, int lda,
                    long sA, long sB, long sC, const float* bias, int act,
                    int cskip, int prods, int batch){
        dim3 g(M/128, (Nc+127)/128, batch);
        gemm_mfma_k<<<g, 256, 0, stream>>>(ah, al, bh, bl, C, chi, clo,
                                           M, Kc, Nc, lda, sA, sB, sC, bias, act, cskip, prods);
    };
    auto gemm64 = [&](const u16* ah, const u16* al, const u16* bh, const u16* bl,
                      float* C, u16* chi, u16* clo, int M, int Kc, int Nc, int lda,
                      long sA, long sB, long sC, const float* bias, int act,
                      int ktrim, int prods, const float* xphi, u16* x3e, float esign,
                      int batch){
        dim3 g(M/64, Nc/64, batch);
        gemm64_k<<<g, 256, 0, stream>>>(ah, al, bh, bl, C, chi, clo,
                                        M, Kc, Nc, lda, sA, sB, sC, bias, act, ktrim, prods,
                                        xphi, x3e, esign);
    };
    const int EW = BN*KK/4/256;

    // ---- weight prep ----
    gflat_k<<<(3*KK*KK+255)/256, 256, 0, stream>>>(gen, GFh);
    {
        dim3 gw(KK/32, KK/32, 6);
        wprep_k<<<gw, 256, 0, stream>>>(Wq, Wk, Wv, Wo, WQKVh, WQKVl, WoTh, WSQKh, WSQKl);
        dim3 g1g(HIDd/32, KK/32, 1);
        split_t_k<<<g1g, 256, 0, stream>>>(W1, W1Th, 0, KK, HIDd, 0L, 0L, 0);
        dim3 g2g(KK/32, HIDd/32, 1);
        split_t_k<<<g2g, 256, 0, stream>>>(W2, W2Th, 0, HIDd, KK, 0L, 0L, 0);
    }

    // ---- phase A: LN1 (+phi-expand) + forward transport ----
    ln_k<<<BN, 256, 0, stream>>>(mu_q, g1, be1, Xb, 0, 0, phi, X3a, 1.f);
    gemm64(X3a, X3a, GFh, GFh, A1b, 0,0, BN, 3*KK, KK, 3*KK, 0,0,0, nullptr, 0, 0, 1,
           phi, X3b, 1.f, 1);
    gemm64(X3b, X3b, GFh, GFh, A2b, 0,0, BN, 3*KK, KK, 3*KK, 0,0,0, nullptr, 0, 0, 1,
           0, 0, 0.f, 1);
    tfinal_k<<<EW, 256, 0, stream>>>(Xb, A1b, A2b, nullptr, Xb, AH, AL);   // mu_g + split

    // ---- phase B: fused projections + attention prep ----
    gemm(AH, AL, WQKVh, WQKVl, QKVb, 0,0, BN, KK, 3*KK, KK, 0,0,0, nullptr, 0, 0, 3, 1);
    split_k<<<(int)(((long)BN*KK+255)/256), 256, 0, stream>>>(sigma_q, AH, AL, (long)BN*KK);
    gemm(AH, AL, WSQKh, WSQKl, SQSKb, 0,0, BN, KK, 2*KK, KK, 0,0,0, nullptr, 0, 0, 3, 1);
    prep2_k<<<BN, 512, 0, stream>>>(QKVb, SQSKb, CFh, CFl, KSh, KSl, Db_);
    {
        dim3 tg(NN/64, HH, BB);
        vtsplit_k<<<tg, 256, 0, stream>>>(QKVb, VTh);
    }

    // ---- phase C: attention, two head-groups of 4 ----
    for (int g = 0; g < 2; ++g){
        size_t cfo = (size_t)g*4*BB*NN*128;
        gemm(CFh+cfo, CFl+cfo, KSh+cfo, KSl+cfo, Sbuf, 0,0,
             NN, 128, NN, 128, (long)NN*128, (long)NN*128, (long)NN*NN,
             nullptr, 0, 1, 3, 16);
        softmax2_k<<<BB*NN, 256, 0, stream>>>(Sbuf, Db_, BMb, BMh, g);
        dim3 pg(NN/64, 16, 1);
        pv_k<<<pg, 256, 0, stream>>>((const u16*)Sbuf, VTh, AH, g);
    }

    // ---- phase D: output proj (+expand) + back transport + fused residual/LN2 ----
    gemm64(AH, AH, WoTh, WoTh, WOb, 0,0, BN, KK, KK, KK, 0,0,0, nullptr, 0, 0, 1,
           phi, X3a, -1.f, 1);
    gemm64(X3a, X3a, GFh, GFh, A1b, 0,0, BN, 3*KK, KK, 3*KK, 0,0,0, nullptr, 0, 0, 1,
           phi, X3b, -1.f, 1);
    gemm64(X3b, X3b, GFh, GFh, A2b, 0,0, BN, 3*KK, KK, 3*KK, 0,0,0, nullptr, 0, 0, 1,
           0, 0, 0.f, 1);
    resln_k<<<BN, 256, 0, stream>>>(WOb, A1b, A2b, mu_q, g2, be2, MRb, MN2b, AH);

    // ---- phase E: 2 VFE iterations ----
    for (int it=0; it<2; ++it){
        const float* hin = (it==0) ? MN2b : Hb;
        gemm(AH, AH, W1Th, W1Th, 0, ZH, 0, BN, KK, HIDd, KK, 0,0,0, bh1, 1, 0, 1, 1);
        gemm64(ZH, ZH, W2Th, W2Th, DRVb, 0,0, BN, HIDd, KK, HIDd, 0,0,0, bh2, 0, 0, 1,
               0, 0, 0.f, 1);
        {
            dim3 tg(KK/32, NN/32, BB);
            split_t_k<<<tg, 256, 0, stream>>>(hin, HTh, 0, NN, KK,
                                              (long)NN*KK, (long)KK*NN, 0);
        }
        {
            dim3 bg(NN/64, KK/64, BB);
            gemm64_k<<<bg, 256, 0, stream>>>(BMh, BMh, HTh, HTh, A1b, 0,0,
                                             NN, NN, KK, NN,
                                             (long)NN*NN, (long)KK*NN, (long)NN*KK,
                                             nullptr, 0, 1, 1, 0, 0, 0.f);
        }
        ffn_update_k<<<EW, 256, 0, stream>>>(hin, Hb, DRVb, A1b, mu_prior, lr, AH,
                                             MRb, MN2b, out, it);
    }

    // ---- phase F: remaining outputs ----
    copy_k<<<EW, 256, 0, stream>>>(sigma_q, out + (size_t)BN*KK, BN*KK/4);
    copy_k<<<(BN*3/4+255)/256, 256, 0, stream>>>(phi, out + 2*(size_t)BN*KK, BN*3/4);

    (void)in_sizes; (void)n_in; (void)out_size; (void)ws_size;
}

// Round 10
// 732.571 us; speedup vs baseline: 1.4737x; 1.0143x over previous
//
#include <hip/hip_runtime.h>
#include <math.h>

#define BB 4
#define NN 1024
#define KK 512
#define HH 8
#define DHh 64
#define HIDd 2048
#define BN (BB*NN)

typedef unsigned short u16;
typedef __attribute__((ext_vector_type(8))) short bf16x8;
typedef __attribute__((ext_vector_type(4))) float f32x4;

// ---------------------------------------------------------------- helpers
__device__ __forceinline__ float gelu_tanh(float x){
    float x3 = x*x*x;
    float t = tanhf(0.7978845608028654f*(x + 0.044715f*x3));
    return 0.5f*x*(1.0f+t);
}
__device__ __forceinline__ u16 f2bf(float x){
    unsigned int u = __float_as_uint(x);
    unsigned int r = (u + 0x7fffu + ((u>>16)&1u)) >> 16;
    return (u16)r;
}
__device__ __forceinline__ float bf2f(u16 b){
    return __uint_as_float(((unsigned int)b)<<16);
}
__device__ __forceinline__ void gload16(const void* g, void* l){
    __builtin_amdgcn_global_load_lds((__attribute__((address_space(1))) void*)g,
                                     (__attribute__((address_space(3))) void*)l, 16, 0, 0);
}
__device__ __forceinline__ void wsplit(u16* hi, u16* lo, size_t o, float v){
    u16 h = f2bf(v);
    hi[o] = h;
    if (lo) lo[o] = f2bf(v - bf2f(h));
}

// ---------------------------------------------------------------- generic transpose-split (used for h^T in phase E)
__global__ __launch_bounds__(256) void split_t_k(
    const float* __restrict__ src, u16* __restrict__ hi, u16* __restrict__ lo,
    int Kc, int Nc, long sS, long sD, int square)
{
    __shared__ float t[32][33];
    const int n0 = blockIdx.x*32, k0 = blockIdx.y*32, bz = blockIdx.z;
    const float* S = src + (long)bz*sS;
    const int tx = threadIdx.x & 31, ty = threadIdx.x >> 5;
    for (int r = ty; r < 32; r += 8){
        float v = S[(long)(k0+r)*Nc + n0+tx];
        if (square) v *= v;
        t[r][tx] = v;
    }
    __syncthreads();
    for (int r = ty; r < 32; r += 8){
        float v = t[tx][r];
        long o = (long)bz*sD + (long)(n0+r)*Kc + k0 + tx;
        wsplit(hi, lo, o, v);
    }
}

// ---------------------------------------------------------------- all weight prep in one dispatch, grid (64,16,9)
__global__ __launch_bounds__(256) void wmega_k(
    const float* __restrict__ Wq, const float* __restrict__ Wk,
    const float* __restrict__ Wv, const float* __restrict__ Wo,
    const float* __restrict__ W1, const float* __restrict__ W2,
    const float* __restrict__ gen,
    u16* __restrict__ WQKVh, u16* __restrict__ WQKVl, u16* __restrict__ WoTh,
    u16* __restrict__ WSQKh, u16* __restrict__ WSQKl,
    u16* __restrict__ W1Th, u16* __restrict__ W2Th, u16* __restrict__ GFh)
{
    const int z = blockIdx.z;
    const int tid = threadIdx.x;
    if (z == 8){   // gflat: copy gen(3,K,K) -> GFh[k][g*512+l]
        if (blockIdx.x >= 48) return;
        const int c0 = blockIdx.x*32, k0 = blockIdx.y*32;
        const int tx = tid&31, ty = tid>>5;
        const int g = c0/KK, l0 = c0%KK;
        for (int r=ty; r<32; r+=8)
            GFh[(size_t)(k0+r)*(3*KK) + c0+tx] =
                f2bf(gen[(size_t)g*KK*KK + (size_t)(k0+r)*KK + l0+tx]);
        return;
    }
    __shared__ float t[32][33];
    const float* src; u16* hi; u16* lo=0; int sq=0;
    int n0, k0, Kc, Nc;
    const size_t KK2 = (size_t)KK*KK;
    if (z < 6){
        if (blockIdx.x >= 16) return;
        n0 = blockIdx.x*32; k0 = blockIdx.y*32; Kc=KK; Nc=KK;
        if      (z==0){ src=Wq; hi=WQKVh;       lo=WQKVl; }
        else if (z==1){ src=Wk; hi=WQKVh+KK2;   lo=WQKVl+KK2; }
        else if (z==2){ src=Wv; hi=WQKVh+2*KK2; lo=WQKVl+2*KK2; }
        else if (z==3){ src=Wo; hi=WoTh; }
        else if (z==4){ src=Wq; hi=WSQKh;       lo=WSQKl; sq=1; }
        else          { src=Wk; hi=WSQKh+KK2;   lo=WSQKl+KK2; sq=1; }
    } else if (z == 6){  // W1 [512][2048] -> [2048][512]
        src=W1; hi=W1Th; Kc=KK; Nc=HIDd;
        n0 = blockIdx.x*32; k0 = blockIdx.y*32;
    } else {             // W2 [2048][512] -> [512][2048]
        src=W2; hi=W2Th; Kc=HIDd; Nc=KK;
        n0 = blockIdx.y*32; k0 = blockIdx.x*32;
    }
    const int tx=tid&31, ty=tid>>5;
    for (int r=ty;r<32;r+=8){
        float v = src[(long)(k0+r)*Nc + n0+tx];
        if (sq) v*=v;
        t[r][tx]=v;
    }
    __syncthreads();
    for (int r=ty;r<32;r+=8){
        float v = t[tx][r];
        long o = (long)(n0+r)*Kc + k0+tx;
        wsplit(hi, lo, o, v);
    }
}

// ---------------------------------------------------------------- MFMA GEMM 128x128, grid: (M/128, N/128, batch)
__global__ __launch_bounds__(256) void gemm_mfma_k(
    const u16* __restrict__ Ah, const u16* __restrict__ Al,
    const u16* __restrict__ Bh, const u16* __restrict__ Bl,
    float* __restrict__ C, u16* __restrict__ Chi, u16* __restrict__ Clo,
    int M, int Kc, int Nc, int lda,
    long sA, long sB, long sC, const float* __restrict__ bias, int act,
    int cskip, int prods)
{
    __shared__ u16 sAh[128*32], sAl[128*32], sBh[128*32], sBl[128*32];
    const int m0 = blockIdx.x*128, n0 = blockIdx.y*128;
    if (cskip == 1 && n0 > m0 + 127) return;
    const int bz = blockIdx.z;
    const u16* gAh = Ah + (long)bz*sA;
    const u16* gAl = Al + (long)bz*sA;
    const u16* gBh = Bh + (long)bz*sB;
    const u16* gBl = Bl + (long)bz*sB;
    const int tid = threadIdx.x;
    const int wave = tid >> 6, lane = tid & 63;
    const int quad = lane >> 4, r16 = lane & 15;
    const int wm = (wave>>1)*64, wn = (wave&1)*64;

    f32x4 acc[4][4];
    #pragma unroll
    for (int i=0;i<4;i++)
        #pragma unroll
        for (int j=0;j<4;j++) acc[i][j] = (f32x4){0.f,0.f,0.f,0.f};

    for (int k0 = 0; k0 < Kc; k0 += 32){
        __syncthreads();
        #pragma unroll
        for (int half=0; half<2; ++half){
            int c = half*256 + tid;
            int row = c >> 2, kg = (c & 3)*8;
            long ga = (long)(m0+row)*lda + k0 + kg;
            long gb = (long)(n0+row)*Kc + k0 + kg;
            gload16(gAh+ga, &sAh[c*8]);
            if (prods == 3) gload16(gAl+ga, &sAl[c*8]);
            gload16(gBh+gb, &sBh[c*8]);
            if (prods >= 2) gload16(gBl+gb, &sBl[c*8]);
        }
        __syncthreads();
        bf16x8 afh[4], afl[4], bfh[4], bfl[4];
        #pragma unroll
        for (int i=0;i<4;i++){
            afh[i] = *(const bf16x8*)&sAh[(wm+i*16+r16)*32 + quad*8];
            bfh[i] = *(const bf16x8*)&sBh[(wn+i*16+r16)*32 + quad*8];
        }
        if (prods >= 2)
            #pragma unroll
            for (int i=0;i<4;i++) bfl[i] = *(const bf16x8*)&sBl[(wn+i*16+r16)*32 + quad*8];
        if (prods == 3)
            #pragma unroll
            for (int i=0;i<4;i++) afl[i] = *(const bf16x8*)&sAl[(wm+i*16+r16)*32 + quad*8];
        #pragma unroll
        for (int i=0;i<4;i++)
            #pragma unroll
            for (int j=0;j<4;j++){
                acc[i][j] = __builtin_amdgcn_mfma_f32_16x16x32_bf16(afh[i], bfh[j], acc[i][j], 0,0,0);
                if (prods >= 2)
                    acc[i][j] = __builtin_amdgcn_mfma_f32_16x16x32_bf16(afh[i], bfl[j], acc[i][j], 0,0,0);
                if (prods == 3)
                    acc[i][j] = __builtin_amdgcn_mfma_f32_16x16x32_bf16(afl[i], bfh[j], acc[i][j], 0,0,0);
            }
    }
    #pragma unroll
    for (int i=0;i<4;i++){
        #pragma unroll
        for (int j=0;j<4;j++){
            int gc = n0 + wn + j*16 + r16;
            if (gc >= Nc) continue;
            float bv = bias ? bias[gc] : 0.f;
            #pragma unroll
            for (int r=0;r<4;r++){
                long gr = m0 + wm + i*16 + quad*4 + r;
                float v = acc[i][j][r] + bv;
                if (act) v = gelu_tanh(v);
                long o = (long)bz*sC + gr*Nc + gc;
                if (C) C[o] = v;
                if (Chi){ u16 t = f2bf(v); Chi[o] = t; if (Clo) Clo[o] = f2bf(v - bf2f(t)); }
            }
        }
    }
}

// ---------------------------------------------------------------- MFMA GEMM 64x64, grid: (M/64, N/64, batch)
// optional epilogues: phi-expand (X3e) or fused FFN update (fmode 1=mid, 2=final)
__global__ __launch_bounds__(256) void gemm64_k(
    const u16* __restrict__ Ah, const u16* __restrict__ Al,
    const u16* __restrict__ Bh, const u16* __restrict__ Bl,
    float* __restrict__ C, u16* __restrict__ Chi, u16* __restrict__ Clo,
    int M, int Kc, int Nc, int lda,
    long sA, long sB, long sC, const float* __restrict__ bias, int act,
    int ktrim, int prods,
    const float* __restrict__ phi, u16* __restrict__ X3e, float esign,
    const float* __restrict__ f_hin, const float* __restrict__ f_bmh,
    const float* __restrict__ f_mup, const float* __restrict__ f_lr,
    u16* __restrict__ f_hh, float* __restrict__ f_hout,
    const float* __restrict__ f_mrb, const float* __restrict__ f_mn2,
    float* __restrict__ f_out, int fmode)
{
    __shared__ u16 sAh[64*32], sAl[64*32], sBh[64*32], sBl[64*32];
    const int m0 = blockIdx.x*64, n0 = blockIdx.y*64;
    const int bz = blockIdx.z;
    const u16* gAh = Ah + (long)bz*sA;
    const u16* gAl = Al + (long)bz*sA;
    const u16* gBh = Bh + (long)bz*sB;
    const u16* gBl = Bl + (long)bz*sB;
    const int tid = threadIdx.x;
    const int wave = tid >> 6, lane = tid & 63;
    const int quad = lane >> 4, r16 = lane & 15;
    const int wr = wave*16;
    const int kend = ktrim ? min(Kc, m0 + 64) : Kc;

    f32x4 acc[4];
    #pragma unroll
    for (int j=0;j<4;j++) acc[j] = (f32x4){0.f,0.f,0.f,0.f};

    for (int k0 = 0; k0 < kend; k0 += 32){
        __syncthreads();
        {
            int row = tid >> 2, kg = (tid & 3)*8;
            long ga = (long)(m0+row)*lda + k0 + kg;
            long gb = (long)(n0+row)*Kc + k0 + kg;
            gload16(gAh+ga, &sAh[tid*8]);
            if (prods == 3) gload16(gAl+ga, &sAl[tid*8]);
            gload16(gBh+gb, &sBh[tid*8]);
            if (prods >= 2) gload16(gBl+gb, &sBl[tid*8]);
        }
        __syncthreads();
        bf16x8 afh = *(const bf16x8*)&sAh[(wr+r16)*32 + quad*8];
        bf16x8 afl;
        if (prods == 3) afl = *(const bf16x8*)&sAl[(wr+r16)*32 + quad*8];
        #pragma unroll
        for (int j=0;j<4;j++){
            bf16x8 bh = *(const bf16x8*)&sBh[(j*16+r16)*32 + quad*8];
            acc[j] = __builtin_amdgcn_mfma_f32_16x16x32_bf16(afh, bh, acc[j], 0,0,0);
            if (prods >= 2){
                bf16x8 bl = *(const bf16x8*)&sBl[(j*16+r16)*32 + quad*8];
                acc[j] = __builtin_amdgcn_mfma_f32_16x16x32_bf16(afh, bl, acc[j], 0,0,0);
            }
            if (prods == 3)
                acc[j] = __builtin_amdgcn_mfma_f32_16x16x32_bf16(afl, bh, acc[j], 0,0,0);
        }
    }
    float lrv = 0.f;
    if (fmode) lrv = *f_lr;
    #pragma unroll
    for (int j=0;j<4;j++){
        int gc = n0 + j*16 + r16;
        float bv = bias ? bias[gc] : 0.f;
        #pragma unroll
        for (int r=0;r<4;r++){
            long gr = m0 + wr + quad*4 + r;
            float v = acc[j][r] + bv;
            if (act) v = gelu_tanh(v);
            long o = (long)bz*sC + gr*Nc + gc;
            if (fmode){
                float hv = f_hin[o];
                float val = hv + lrv*(v - (1e-3f*(hv - f_mup[o]) + (hv - f_bmh[o])));
                if (fmode == 1){ f_hout[o] = val; f_hh[o] = f2bf(val); }
                else           { f_out[o] = f_mrb[o] + val - f_mn2[o]; }
            } else {
                if (C) C[o] = v;
                if (Chi){ u16 t = f2bf(v); Chi[o] = t; if (Clo) Clo[o] = f2bf(v - bf2f(t)); }
                if (X3e){
                    const float* ph = phi + gr*3;
                    size_t b = (size_t)gr*(3*KK) + gc;
                    X3e[b]      = f2bf(esign*ph[0]*v);
                    X3e[b+KK]   = f2bf(esign*ph[1]*v);
                    X3e[b+2*KK] = f2bf(esign*ph[2]*v);
                }
            }
        }
    }
}

// ---------------------------------------------------------------- LayerNorm + phi-expand + sigma split
__global__ __launch_bounds__(256) void ln_k(
    const float* __restrict__ x, const float* __restrict__ g,
    const float* __restrict__ be, float* __restrict__ y,
    const float* __restrict__ phi, u16* __restrict__ x3, float esign,
    const float* __restrict__ sg, u16* __restrict__ sgh, u16* __restrict__ sgl)
{
    __shared__ float sh[8];
    const int r = blockIdx.x, tid = threadIdx.x;
    const float* xr = x + (long)r*KK;
    float2 v = *(const float2*)(xr + tid*2);
    float s = v.x+v.y, s2 = v.x*v.x+v.y*v.y;
    #pragma unroll
    for (int o=32;o>0;o>>=1){ s += __shfl_down(s,o); s2 += __shfl_down(s2,o); }
    if ((tid&63)==0){ sh[tid>>6]=s; sh[4+(tid>>6)]=s2; }
    __syncthreads();
    s  = sh[0]+sh[1]+sh[2]+sh[3];
    s2 = sh[4]+sh[5]+sh[6]+sh[7];
    const float mean = s*(1.f/KK);
    const float var  = s2*(1.f/KK) - mean*mean;
    const float rs = rsqrtf(var + 1e-5f);
    float2 gg = *(const float2*)(g + tid*2);
    float2 bb = *(const float2*)(be + tid*2);
    float ox = (v.x-mean)*rs*gg.x + bb.x;
    float oy = (v.y-mean)*rs*gg.y + bb.y;
    long o = (long)r*KK + tid*2;
    *(float2*)(y + o) = make_float2(ox, oy);
    if (x3){
        const float* ph = phi + r*3;
        size_t b = (size_t)r*(3*KK) + tid*2;
        #pragma unroll
        for (int gg2=0; gg2<3; ++gg2){
            float p = esign*ph[gg2];
            x3[b + gg2*KK]     = f2bf(p*ox);
            x3[b + gg2*KK + 1] = f2bf(p*oy);
        }
    }
    if (sgh){
        float2 sv = *(const float2*)(sg + o);
        wsplit(sgh, sgl, o,   sv.x);
        wsplit(sgh, sgl, o+1, sv.y);
    }
}

// ---------------------------------------------------------------- fused residual + LayerNorm (phase D)
__global__ __launch_bounds__(256) void resln_k(
    const float* __restrict__ wo, const float* __restrict__ a1,
    const float* __restrict__ a2, const float* __restrict__ res,
    const float* __restrict__ g, const float* __restrict__ be,
    float* __restrict__ mrb, float* __restrict__ mn2, u16* __restrict__ yh)
{
    __shared__ float sh[8];
    const int r = blockIdx.x, tid = threadIdx.x;
    long o = (long)r*KK + tid*2;
    float2 xv = *(const float2*)(wo + o);
    float2 v1 = *(const float2*)(a1 + o);
    float2 v2 = *(const float2*)(a2 + o);
    float2 rv = *(const float2*)(res + o);
    float mx = xv.x + v1.x + 0.5f*v2.x + rv.x;
    float my = xv.y + v1.y + 0.5f*v2.y + rv.y;
    *(float2*)(mrb + o) = make_float2(mx, my);
    float s = mx+my, s2 = mx*mx+my*my;
    #pragma unroll
    for (int of=32;of>0;of>>=1){ s += __shfl_down(s,of); s2 += __shfl_down(s2,of); }
    if ((tid&63)==0){ sh[tid>>6]=s; sh[4+(tid>>6)]=s2; }
    __syncthreads();
    s  = sh[0]+sh[1]+sh[2]+sh[3];
    s2 = sh[4]+sh[5]+sh[6]+sh[7];
    const float mean = s*(1.f/KK);
    const float var  = s2*(1.f/KK) - mean*mean;
    const float rs = rsqrtf(var + 1e-5f);
    float2 gg = *(const float2*)(g + tid*2);
    float2 bb = *(const float2*)(be + tid*2);
    float ox = (mx-mean)*rs*gg.x + bb.x;
    float oy = (my-mean)*rs*gg.y + bb.y;
    *(float2*)(mn2 + o) = make_float2(ox, oy);
    yh[o] = f2bf(ox); yh[o+1] = f2bf(oy);
}

// ---------------------------------------------------------------- elementwise
__global__ void tfinal_k(const float* __restrict__ x, const float* __restrict__ a1,
                         const float* __restrict__ a2,
                         float* __restrict__ out, u16* __restrict__ oh, u16* __restrict__ ol){
    int i = blockIdx.x*256 + threadIdx.x;
    if (i >= BN*KK/4) return;
    float4 xv = ((const float4*)x)[i];
    float4 v1 = ((const float4*)a1)[i];
    float4 v2 = ((const float4*)a2)[i];
    float4 o;
    o.x = xv.x + v1.x + 0.5f*v2.x;
    o.y = xv.y + v1.y + 0.5f*v2.y;
    o.z = xv.z + v1.z + 0.5f*v2.z;
    o.w = xv.w + v1.w + 0.5f*v2.w;
    ((float4*)out)[i] = o;
    long ob = (long)i*4;
    wsplit(oh, ol, ob+0, o.x); wsplit(oh, ol, ob+1, o.y);
    wsplit(oh, ol, ob+2, o.z); wsplit(oh, ol, ob+3, o.w);
}
__global__ void outcopy_k(const float* __restrict__ sigma, const float* __restrict__ phi,
                          float* __restrict__ out){
    int i = blockIdx.x*256 + threadIdx.x;
    const int NS = BN*KK/4;
    if (i < NS){
        ((float4*)(out + (size_t)BN*KK))[i] = ((const float4*)sigma)[i];
    } else if (i < NS + BN*3/4){
        int j = i - NS;
        ((float4*)(out + 2*(size_t)BN*KK))[j] = ((const float4*)phi)[j];
    }
}

// ---------------------------------------------------------------- merged attention prep + V transpose
__global__ __launch_bounds__(512) void prepvt_k(
    const float* __restrict__ QKV, const float* __restrict__ SQSK,
    u16* __restrict__ CFh, u16* __restrict__ CFl,
    u16* __restrict__ KSh, u16* __restrict__ KSl, float* __restrict__ dvec,
    u16* __restrict__ VTh)
{
    __shared__ float t[64][65];
    const int bx = blockIdx.x;
    const int tid = threadIdx.x;
    if (bx < BN){
        const int bn = bx;
        const int b = bn / NN, n = bn % NN;
        const int h = tid >> 6, d = tid & 63;
        float q  = QKV[(size_t)bn*1536 + h*DHh + d];
        float k  = QKV[(size_t)bn*1536 + KK + h*DHh + d];
        float sq = SQSK[(size_t)bn*1024 + h*DHh + d] + 1e-8f;
        float sk = SQSK[(size_t)bn*1024 + KK + h*DHh + d] + 1e-8f;
        float inv = 1.f/sq;
        float nqi = -2.f*q*inv;
        float skk = sk + k*k;
        const size_t base = ((size_t)(h*BB + b)*NN + n)*128;
        wsplit(CFh, CFl, base+d,    inv);
        wsplit(CFh, CFl, base+64+d, nqi);
        wsplit(KSh, KSl, base+d,    skk);
        wsplit(KSh, KSl, base+64+d, k);
        float dv = __logf(sk);
        #pragma unroll
        for (int o=32;o>0;o>>=1) dv += __shfl_down(dv,o);
        if (d==0) dvec[((size_t)h*BB + b)*NN + n] = dv;
        return;
    }
    const int idx = bx - BN;
    const int n0 = (idx & 15)*64;
    const int h = (idx>>4)&7;
    const int b = idx>>7;
    const int c4 = (tid & 15) * 4;
    const int r0 = tid >> 4;     // 0..31
    for (int rr = r0; rr < 64; rr += 32){
        float4 v = *(const float4*)(QKV + (size_t)(b*NN + n0 + rr)*1536 + 1024 + h*DHh + c4);
        t[c4+0][rr] = v.x; t[c4+1][rr] = v.y; t[c4+2][rr] = v.z; t[c4+3][rr] = v.w;
    }
    __syncthreads();
    for (int dd = r0; dd < 64; dd += 32){
        size_t base = ((size_t)(h*BB + b)*64 + dd)*NN + n0 + c4;
        #pragma unroll
        for (int q=0;q<4;q++) VTh[base+q] = f2bf(t[dd][c4+q]);
    }
}

// ---------------------------------------------------------------- softmax for a head-group of 4
__global__ __launch_bounds__(256) void softmax2_k(
    float* __restrict__ S, const float* __restrict__ dvec,
    float* __restrict__ betam, u16* __restrict__ BMh, int g)
{
    __shared__ float s_sc[NN];
    __shared__ float s_bm[NN];
    __shared__ float s_red[4];
    const int tid = threadIdx.x;
    const int b = blockIdx.x / NN, i = blockIdx.x % NN;
    const int L = i + 1;
    for (int j=tid;j<NN;j+=256) s_bm[j]=0.f;
    for (int hg=0; hg<4; ++hg){
        const int z = hg*BB + b;
        float* row = S + ((long)z*NN + i)*NN;
        const float* dp = dvec + ((size_t)(g*4+hg)*BB + b)*NN;
        float lm = -3.0e38f;
        for (int j=tid;j<L;j+=256){
            float sc = -0.5f*row[j] + 0.5f*dp[j];
            s_sc[j] = sc;
            lm = fmaxf(lm, sc);
        }
        #pragma unroll
        for (int o=32;o>0;o>>=1) lm = fmaxf(lm, __shfl_xor(lm, o));
        __syncthreads();
        if ((tid&63)==0) s_red[tid>>6] = lm;
        __syncthreads();
        const float mx = fmaxf(fmaxf(s_red[0],s_red[1]), fmaxf(s_red[2],s_red[3]));
        float ps = 0.f;
        for (int j=tid;j<L;j+=256){
            float e = __expf(s_sc[j]-mx);
            s_sc[j] = e;
            ps += e;
        }
        #pragma unroll
        for (int o=32;o>0;o>>=1) ps += __shfl_xor(ps, o);
        __syncthreads();
        if ((tid&63)==0) s_red[tid>>6] = ps;
        __syncthreads();
        const float isum = 1.f/(s_red[0]+s_red[1]+s_red[2]+s_red[3]);
        u16* brow = (u16*)row;
        for (int j=tid;j<NN;j+=256){
            if (j < L){
                float w = s_sc[j]*isum;
                brow[j] = f2bf(w);
                s_bm[j] += 0.125f*w;
            } else {
                brow[j] = 0;
            }
        }
        __syncthreads();
    }
    const long bmrow = ((long)b*NN + i)*NN;
    if (g == 0){
        for (int j=tid;j<NN;j+=256) betam[bmrow+j] = s_bm[j];
    } else {
        for (int j=tid;j<NN;j+=256) BMh[bmrow+j] = f2bf(betam[bmrow+j] + s_bm[j]);
    }
}

// ---------------------------------------------------------------- PV
__global__ __launch_bounds__(256) void pv_k(
    const u16* __restrict__ Sbeta,
    const u16* __restrict__ VTh,
    u16* __restrict__ xh, int g)
{
    __shared__ u16 sA[64*64];
    __shared__ u16 sBh[64*64];
    const int m0 = blockIdx.x*64;
    const int z16 = blockIdx.y;
    const int b = z16 & 3, hg = z16 >> 2;
    const int head = g*4 + hg;
    const int vtz = head*BB + b;
    const int tid = threadIdx.x;
    const int wave = tid>>6, lane = tid&63;
    const int quad = lane>>4, r16 = lane&15;
    f32x4 acc[4];
    #pragma unroll
    for (int j=0;j<4;j++) acc[j]=(f32x4){0.f,0.f,0.f,0.f};
    const int jmax = m0 + 64;
    for (int j0 = 0; j0 < jmax; j0 += 64){
        __syncthreads();
        int c = tid;
        #pragma unroll
        for (int rep=0; rep<2; ++rep, c+=256){
            int row = c >> 3, k8 = (c&7)*8;
            gload16(Sbeta + ((size_t)(z16*NN + m0 + row))*(2*NN) + j0 + k8, &sA[c*8]);
            gload16(VTh + ((size_t)(vtz*64 + row))*NN + j0 + k8, &sBh[c*8]);
        }
        __syncthreads();
        #pragma unroll
        for (int kk=0; kk<2; ++kk){
            bf16x8 af = *(const bf16x8*)&sA[(wave*16 + r16)*64 + kk*32 + quad*8];
            #pragma unroll
            for (int nj=0; nj<4; ++nj){
                bf16x8 bh = *(const bf16x8*)&sBh[(nj*16 + r16)*64 + kk*32 + quad*8];
                acc[nj] = __builtin_amdgcn_mfma_f32_16x16x32_bf16(af, bh, acc[nj], 0,0,0);
            }
        }
    }
    #pragma unroll
    for (int nj=0;nj<4;nj++){
        #pragma unroll
        for (int r=0;r<4;r++){
            int i = m0 + wave*16 + quad*4 + r;
            int d = nj*16 + r16;
            size_t o = ((size_t)(b*NN)+i)*KK + head*64 + d;
            xh[o] = f2bf(acc[nj][r]);
        }
    }
}

// ---------------------------------------------------------------- launch
extern "C" void kernel_launch(void* const* d_in, const int* in_sizes, int n_in,
                              void* d_out, int out_size, void* d_ws, size_t ws_size,
                              hipStream_t stream) {
    const float* mu_q    = (const float*)d_in[0];
    const float* sigma_q = (const float*)d_in[1];
    const float* phi     = (const float*)d_in[2];
    const float* gen     = (const float*)d_in[3];
    const float* mu_prior= (const float*)d_in[5];
    const float* Wq = (const float*)d_in[6];
    const float* Wk = (const float*)d_in[7];
    const float* Wv = (const float*)d_in[8];
    const float* Wo = (const float*)d_in[9];
    const float* g1 = (const float*)d_in[10];
    const float* be1= (const float*)d_in[11];
    const float* g2 = (const float*)d_in[12];
    const float* be2= (const float*)d_in[13];
    const float* W1 = (const float*)d_in[14];
    const float* bh1= (const float*)d_in[15];
    const float* W2 = (const float*)d_in[16];
    const float* bh2= (const float*)d_in[17];
    const float* lr = (const float*)d_in[18];
    float* out = (float*)d_out;

    float* w = (float*)d_ws;
    size_t off = 0;
    auto alloc = [&](size_t n){ float* p = w + off; off += (n+3)&~(size_t)3; return p; };
    auto ualloc = [&](size_t n){ return (u16*)alloc((n+1)/2); };

    float* Xb   = alloc((size_t)BN*KK);        // mu_n -> mu_g -> mu_n2
    float* A1b  = alloc((size_t)BN*KK);        // a1 / bmh
    float* A2b  = alloc((size_t)BN*KK);        // a2
    float* QKVb = alloc((size_t)BN*3*KK);      // QKV; later WOb / Hb / MRb
    float* SQSKb= alloc((size_t)BN*2*KK);
    float* REG  = alloc((size_t)16*NN*NN);     // X3a/X3b/SGh/SGl | Sbuf | ZH
    float* Sbuf = REG;
    u16*  X3a   = (u16*)REG;
    u16*  X3b   = X3a + (size_t)BN*3*KK;
    u16*  SGh   = X3b + (size_t)BN*3*KK;
    u16*  SGl   = SGh + (size_t)BN*KK;
    u16*  ZH    = (u16*)REG;
    float* Db_  = alloc((size_t)HH*BB*NN);
    float* BMb  = alloc((size_t)BB*NN*NN);
    u16* AH  = ualloc((size_t)BN*HIDd); u16* AL  = ualloc((size_t)BN*HIDd);
    u16* CFh = AH;
    u16* CFl = AH + (size_t)HH*BB*NN*128;
    u16* KSh = AL;
    u16* KSl = AL + (size_t)HH*BB*NN*128;
    u16* VTh = ualloc((size_t)HH*BB*64*NN);
    u16* GFh = ualloc((size_t)3*KK*KK);
    u16* WQKVh= ualloc((size_t)3*KK*KK); u16* WQKVl= ualloc((size_t)3*KK*KK);
    u16* WSQKh= ualloc((size_t)2*KK*KK); u16* WSQKl= ualloc((size_t)2*KK*KK);
    u16* WoTh= ualloc((size_t)KK*KK);
    u16* W1Th= ualloc((size_t)KK*HIDd);
    u16* W2Th= ualloc((size_t)KK*HIDd);
    u16* BMh = ualloc((size_t)BB*NN*NN);
    u16* HTh = ualloc((size_t)BB*KK*NN);
    float* WOb = QKVb;
    float* Hb  = QKVb + (size_t)BN*KK;
    float* MRb = QKVb + 2*(size_t)BN*KK;
    float* MN2b= Xb;

    auto gemm = [&](const u16* ah, const u16* al, const u16* bh, const u16* bl,
                    float* C, u16* chi, u16* clo, int M, int Kc, int Nc, int lda,
                    long sA, long sB, long sC, const float* bias, int act,
                    int cskip, int prods, int batch){
        dim3 g(M/128, (Nc+127)/128, batch);
        gemm_mfma_k<<<g, 256, 0, stream>>>(ah, al, bh, bl, C, chi, clo,
                                           M, Kc, Nc, lda, sA, sB, sC, bias, act, cskip, prods);
    };
    auto gemm64 = [&](const u16* ah, const u16* al, const u16* bh, const u16* bl,
                      float* C, u16* chi, u16* clo, int M, int Kc, int Nc, int lda,
                      long sA, long sB, long sC, const float* bias, int act,
                      int ktrim, int prods, const float* xphi, u16* x3e, float esign,
                      int batch){
        dim3 g(M/64, Nc/64, batch);
        gemm64_k<<<g, 256, 0, stream>>>(ah, al, bh, bl, C, chi, clo,
                                        M, Kc, Nc, lda, sA, sB, sC, bias, act, ktrim, prods,
                                        xphi, x3e, esign,
                                        0,0,0,0,0,0,0,0,0,0);
    };
    const int EW = BN*KK/4/256;

    // ---- weight prep: one dispatch ----
    {
        dim3 gw(64, 16, 9);
        wmega_k<<<gw, 256, 0, stream>>>(Wq, Wk, Wv, Wo, W1, W2, gen,
                                        WQKVh, WQKVl, WoTh, WSQKh, WSQKl,
                                        W1Th, W2Th, GFh);
    }

    // ---- phase A: LN1 (+phi-expand, +sigma split) + forward transport ----
    ln_k<<<BN, 256, 0, stream>>>(mu_q, g1, be1, Xb, phi, X3a, 1.f, sigma_q, SGh, SGl);
    gemm64(X3a, X3a, GFh, GFh, A1b, 0,0, BN, 3*KK, KK, 3*KK, 0,0,0, nullptr, 0, 0, 1,
           phi, X3b, 1.f, 1);
    gemm64(X3b, X3b, GFh, GFh, A2b, 0,0, BN, 3*KK, KK, 3*KK, 0,0,0, nullptr, 0, 0, 1,
           0, 0, 0.f, 1);
    tfinal_k<<<EW, 256, 0, stream>>>(Xb, A1b, A2b, Xb, AH, AL);            // mu_g + split

    // ---- phase B: projections + merged attention prep ----
    gemm(AH, AL, WQKVh, WQKVl, QKVb, 0,0, BN, KK, 3*KK, KK, 0,0,0, nullptr, 0, 0, 3, 1);
    gemm(SGh, SGl, WSQKh, WSQKl, SQSKb, 0,0, BN, KK, 2*KK, KK, 0,0,0, nullptr, 0, 0, 3, 1);
    prepvt_k<<<BN + 512, 512, 0, stream>>>(QKVb, SQSKb, CFh, CFl, KSh, KSl, Db_, VTh);

    // ---- phase C: attention, two head-groups of 4 ----
    for (int g = 0; g < 2; ++g){
        size_t cfo = (size_t)g*4*BB*NN*128;
        gemm(CFh+cfo, CFl+cfo, KSh+cfo, KSl+cfo, Sbuf, 0,0,
             NN, 128, NN, 128, (long)NN*128, (long)NN*128, (long)NN*NN,
             nullptr, 0, 1, 3, 16);
        softmax2_k<<<BB*NN, 256, 0, stream>>>(Sbuf, Db_, BMb, BMh, g);
        dim3 pg(NN/64, 16, 1);
        pv_k<<<pg, 256, 0, stream>>>((const u16*)Sbuf, VTh, AH, g);
    }

    // ---- phase D: output proj (+expand) + back transport + fused residual/LN2 ----
    gemm64(AH, AH, WoTh, WoTh, WOb, 0,0, BN, KK, KK, KK, 0,0,0, nullptr, 0, 0, 1,
           phi, X3a, -1.f, 1);
    gemm64(X3a, X3a, GFh, GFh, A1b, 0,0, BN, 3*KK, KK, 3*KK, 0,0,0, nullptr, 0, 0, 1,
           phi, X3b, -1.f, 1);
    gemm64(X3b, X3b, GFh, GFh, A2b, 0,0, BN, 3*KK, KK, 3*KK, 0,0,0, nullptr, 0, 0, 1,
           0, 0, 0.f, 1);
    resln_k<<<BN, 256, 0, stream>>>(WOb, A1b, A2b, mu_q, g2, be2, MRb, MN2b, AH);

    // ---- phase E: 2 VFE iterations (bmh first, then W1, then W2 with fused update) ----
    for (int it=0; it<2; ++it){
        const float* hin = (it==0) ? MN2b : Hb;
        {
            dim3 tg(KK/32, NN/32, BB);
            split_t_k<<<tg, 256, 0, stream>>>(hin, HTh, 0, NN, KK,
                                              (long)NN*KK, (long)KK*NN, 0);
        }
        {
            dim3 bg(NN/64, KK/64, BB);
            gemm64_k<<<bg, 256, 0, stream>>>(BMh, BMh, HTh, HTh, A1b, 0,0,
                                             NN, NN, KK, NN,
                                             (long)NN*NN, (long)KK*NN, (long)NN*KK,
                                             nullptr, 0, 1, 1, 0, 0, 0.f,
                                             0,0,0,0,0,0,0,0,0,0);
        }
        gemm(AH, AH, W1Th, W1Th, 0, ZH, 0, BN, KK, HIDd, KK, 0,0,0, bh1, 1, 0, 1, 1);
        {   // W2 + fused FFN update
            dim3 wg(BN/64, KK/64, 1);
            gemm64_k<<<wg, 256, 0, stream>>>(ZH, ZH, W2Th, W2Th, 0,0,0,
                                             BN, HIDd, KK, HIDd, 0,0,0, bh2, 0, 0, 1,
                                             0, 0, 0.f,
                                             hin, A1b, mu_prior, lr, AH, Hb, MRb, MN2b, out,
                                             (it==0) ? 1 : 2);
        }
    }

    // ---- phase F: remaining outputs (one dispatch) ----
    outcopy_k<<<(BN*KK/4 + BN*3/4 + 255)/256, 256, 0, stream>>>(sigma_q, phi, out);

    (void)in_sizes; (void)n_in; (void)out_size; (void)ws_size;
}